// Round 6
// baseline (6809.457 us; speedup 1.0000x reference)
//
#include <hip/hip_runtime.h>

typedef short bf16x8 __attribute__((ext_vector_type(8)));
typedef float f32x4 __attribute__((ext_vector_type(4)));

static __device__ __forceinline__ unsigned short f2bf(float f) {
    unsigned int u = __float_as_uint(f);
    unsigned int r = (u + 0x7fffu + ((u >> 16) & 1u)) >> 16;
    return (unsigned short)r;
}
static __device__ __forceinline__ float sigmoidf_(float x) {
    return 1.0f / (1.0f + __expf(-x));
}
static __device__ __forceinline__ float tanhf_(float x) {
    return 2.0f / (1.0f + __expf(-2.0f * x)) - 1.0f;
}

// write-through store to the device coherence point (no dirty L2 line left behind)
static __device__ __forceinline__ void stc4(float* p, float v) {
    __hip_atomic_store((unsigned*)p, __float_as_uint(v),
                       __ATOMIC_RELAXED, __HIP_MEMORY_SCOPE_AGENT);
}

// async global -> LDS, 16 B per lane. lds ptr must be wave-uniform base; HW adds lane*16.
static __device__ __forceinline__ void dma16(const float* g, float* l) {
    __builtin_amdgcn_global_load_lds((const __attribute__((address_space(1))) void*)g,
                                     (__attribute__((address_space(3))) void*)l, 16, 0, 0);
}

// ---- activation layout: element (k,b) at ((k>>2)*32 + b)*4 + (k&3)  (k4-interleaved) ----

// ---------------- grid barrier ----------------
// Arrival: 64 distributed padded counters (relaxed agent RMW after vmcnt drain — sc1 stores
// are already at the coherence point). Master block 0 wave-0 sums; relaxed gen release.
// Exit: ONE agent-acquire fence per block (L1+L2 invalidate) so subsequent CACHED activation
// reads are fresh; weights were never L2-resident so the invalidate costs ~nothing.
// bar layout (uint): cnt[i] at bar[i*32], i=0..63 ; gen at bar[2048]
static __device__ __forceinline__ void gbar(unsigned* bar, unsigned target) {
    asm volatile("s_waitcnt vmcnt(0) lgkmcnt(0)" ::: "memory");
    __builtin_amdgcn_s_barrier();
    const int tid = threadIdx.x;
    if (tid == 0) {
        __hip_atomic_fetch_add(bar + ((blockIdx.x & 63) << 5), 1u,
                               __ATOMIC_RELAXED, __HIP_MEMORY_SCOPE_AGENT);
    }
    if (blockIdx.x == 0) {
        if (tid < 64) {
            const unsigned tgt = target << 9;   // 512 * target
            for (;;) {
                unsigned v = __hip_atomic_load(bar + (tid << 5), __ATOMIC_RELAXED,
                                               __HIP_MEMORY_SCOPE_AGENT);
                v += __shfl_xor(v, 1);
                v += __shfl_xor(v, 2);
                v += __shfl_xor(v, 4);
                v += __shfl_xor(v, 8);
                v += __shfl_xor(v, 16);
                v += __shfl_xor(v, 32);
                if (v >= tgt) break;
                __builtin_amdgcn_s_sleep(1);
            }
            if (tid == 0) {
                __hip_atomic_store(bar + 2048, target, __ATOMIC_RELAXED,
                                   __HIP_MEMORY_SCOPE_AGENT);
            }
        }
    } else {
        if (tid == 0) {
            while (__hip_atomic_load(bar + 2048, __ATOMIC_RELAXED,
                                     __HIP_MEMORY_SCOPE_AGENT) < target)
                __builtin_amdgcn_s_sleep(1);
        }
    }
    if (tid == 0) {
        __builtin_amdgcn_fence(__ATOMIC_ACQUIRE, "agent");   // L1+L2 invalidate
    }
    __builtin_amdgcn_s_barrier();
    asm volatile("" ::: "memory");
}

// ---------------- persistent recurrence kernel ----------------
struct RArgs {
    const float *m1W, *m1b, *Wih1, *Whh1, *bih1, *bhh1;
    const float *m2W, *m2b, *Wih2, *Whh2, *bih2, *bhh2;
    float *XT, *st, *hs;
    unsigned* bar;
};

__global__ __launch_bounds__(256, 2) void reck(RArgs A) {
    __shared__ float wbuf[2][4096];   // 32 KB: mog weight double-buffer / lstm chunk buf P
    __shared__ float lext[4096];      // 16 KB: lstm chunk buf Q
    __shared__ float red2[4][16][32]; // 8 KB reduction scratch

    const int tid = threadIdx.x;
    const int lane = tid & 63;
    const int wv = tid >> 6;
    const int b = tid & 31;
    const int kq = tid >> 5;          // 0..7
    const int blk = blockIdx.x;
    const bool L1 = blk < 256;
    const int g = L1 ? blk : blk - 256;
    const int j0 = g * 4;

    const float* mW  = L1 ? A.m1W : A.m2W;
    const float* mb  = L1 ? A.m1b : A.m2b;
    const float* Wih = L1 ? A.Wih1 : A.Wih2;
    const float* Whh = L1 ? A.Whh1 : A.Whh2;
    const float* bih = L1 ? A.bih1 : A.bih2;
    const float* bhh = L1 ? A.bhh1 : A.bhh2;

    float* h   = A.st + (L1 ? 0 : 65536);
    float* cc  = A.st + (L1 ? 32768 : 98304);   // block-local: stays normally cached
    float* hm  = A.st + (L1 ? 131072 : 163840);
    float* x2v = A.st + 196608;

    // prologue: mog phase-0 weights -> wbuf[0]
    {
        const float* src = mW + (size_t)j0 * 1024 + wv * 1024;
        float* dl = &wbuf[0][wv * 1024];
#pragma unroll
        for (int i = 0; i < 4; ++i) dma16(src + i * 256 + lane * 4, dl + i * 256);
    }
    asm volatile("s_waitcnt vmcnt(0)" ::: "memory");
    __builtin_amdgcn_s_barrier();

    unsigned bcnt = 0;
    int cur = 0;
    for (int s = 0; s <= 64; ++s) {
        const bool act = L1 ? (s < 64) : (s > 0);
        const int t = L1 ? s : s - 1;
        float* x = L1 ? (A.XT + (size_t)(act ? t : 0) * 32768)
                      : (x2v + (size_t)((act ? t : 0) & 1) * 32768);

        for (int ph = 0; ph < 5; ++ph) {
            // issue next mog-phase weight DMA into the other buffer
            {
                const float* src = mW + (size_t)((ph + 1) % 5) * 1048576
                                      + (size_t)j0 * 1024 + wv * 1024;
                float* dl = &wbuf[cur ^ 1][wv * 1024];
#pragma unroll
                for (int i = 0; i < 4; ++i) dma16(src + i * 256 + lane * 4, dl + i * 256);
            }
            if (act) {
                const float *gin, *srcv; float* dstv;
                switch (ph) {
                    default:
                    case 0: gin = h;  srcv = x;  dstv = x;  break;
                    case 1: gin = x;  srcv = h;  dstv = hm; break;
                    case 2: gin = hm; srcv = x;  dstv = x;  break;
                    case 3: gin = x;  srcv = hm; dstv = hm; break;
                    case 4: gin = hm; srcv = x;  dstv = x;  break;
                }
                const float* gp = gin + kq * 4096 + b * 4;
                const float* wl = &wbuf[cur][kq * 128];
                float a0 = 0.f, a1 = 0.f, a2 = 0.f, a3 = 0.f;
#pragma unroll 8
                for (int c2 = 0; c2 < 32; ++c2) {
                    float4 a = *(const float4*)(gp + c2 * 128);   // cached read
                    float4 w = *(const float4*)(wl + c2 * 4);
                    a0 += a.x * w.x + a.y * w.y + a.z * w.z + a.w * w.w;
                    w = *(const float4*)(wl + 1024 + c2 * 4);
                    a1 += a.x * w.x + a.y * w.y + a.z * w.z + a.w * w.w;
                    w = *(const float4*)(wl + 2048 + c2 * 4);
                    a2 += a.x * w.x + a.y * w.y + a.z * w.z + a.w * w.w;
                    w = *(const float4*)(wl + 3072 + c2 * 4);
                    a3 += a.x * w.x + a.y * w.y + a.z * w.z + a.w * w.w;
                }
                a0 += __shfl_xor(a0, 32);
                a1 += __shfl_xor(a1, 32);
                a2 += __shfl_xor(a2, 32);
                a3 += __shfl_xor(a3, 32);
                if ((tid & 32) == 0) {
                    red2[wv][0][b] = a0; red2[wv][1][b] = a1;
                    red2[wv][2][b] = a2; red2[wv][3][b] = a3;
                }
                __syncthreads();
                if (tid < 128) {
                    int j = tid >> 5, bb = tid & 31;
                    float ssum = (red2[0][j][bb] + red2[1][j][bb])
                               + (red2[2][j][bb] + red2[3][j][bb]);
                    int ja = j0 + j;
                    ssum += mb[ph * 1024 + ja];
                    float gmul = 2.0f * sigmoidf_(ssum);
                    int idx = ((ja >> 2) * 32 + bb) * 4 + (ja & 3);
                    stc4(&dstv[idx], gmul * srcv[idx]);   // cached read, write-through store
                }
            }
            gbar(A.bar, ++bcnt);
            cur ^= 1;
        }

        // ---------------- LSTM slot: stream 8x16KB weight chunks through LDS ----------------
        {
            float* P = &wbuf[cur ^ 1][0];
            float* Q = &lext[0];
            if (act) {
                {
                    const float* WS = Wih;
#pragma unroll
                    for (int i = 0; i < 4; ++i) {
                        int rr = wv * 4 + i;
                        int R = (rr >> 2) * 1024 + j0 + (rr & 3);
                        dma16(WS + (size_t)R * 1024 + lane * 4, Q + rr * 256);
                    }
                }
                asm volatile("s_waitcnt vmcnt(0)" ::: "memory");
                __builtin_amdgcn_s_barrier();

                float acc[16];
#pragma unroll
                for (int i = 0; i < 16; ++i) acc[i] = 0.f;

                for (int c = 0; c < 8; ++c) {
                    float* bc = (c & 1) ? P : Q;
                    const int side = c >> 2, kseg = c & 3;
                    const float* ab = (side ? hm : x) + (size_t)(kseg * 64 + kq * 8) * 128 + b * 4;
                    float4 av[8];
#pragma unroll
                    for (int i = 0; i < 8; ++i) av[i] = *(const float4*)(ab + i * 128);  // cached
                    __builtin_amdgcn_sched_barrier(0);
                    if (c < 7) {
                        const int cn = c + 1;
                        const int nside = cn >> 2, nkseg = cn & 3;
                        const float* WS = nside ? Whh : Wih;
                        float* nb2 = (c & 1) ? Q : P;
#pragma unroll
                        for (int i = 0; i < 4; ++i) {
                            int rr = wv * 4 + i;
                            int R = (rr >> 2) * 1024 + j0 + (rr & 3);
                            dma16(WS + (size_t)R * 1024 + nkseg * 256 + lane * 4, nb2 + rr * 256);
                        }
                    }
                    __builtin_amdgcn_sched_barrier(0);
#pragma unroll
                    for (int i = 0; i < 8; ++i) {
#pragma unroll
                        for (int rr = 0; rr < 16; ++rr) {
                            float4 w = *(const float4*)(bc + rr * 256 + kq * 32 + i * 4);
                            acc[rr] += av[i].x * w.x + av[i].y * w.y
                                     + av[i].z * w.z + av[i].w * w.w;
                        }
                    }
                    asm volatile("s_waitcnt vmcnt(0) lgkmcnt(0)" ::: "memory");
                    __builtin_amdgcn_s_barrier();
                }

#pragma unroll
                for (int i = 0; i < 16; ++i) acc[i] += __shfl_xor(acc[i], 32);
                if ((tid & 32) == 0) {
#pragma unroll
                    for (int i = 0; i < 16; ++i) red2[wv][i][b] = acc[i];
                }
                __syncthreads();
                if (tid < 128) {
                    int jj = tid >> 5, bb = tid & 31;
                    int ja = j0 + jj;
                    float gi = 0.f, gf = 0.f, gg = 0.f, go = 0.f;
#pragma unroll
                    for (int w = 0; w < 4; ++w) {
                        gi += red2[w][0 + jj][bb];
                        gf += red2[w][4 + jj][bb];
                        gg += red2[w][8 + jj][bb];
                        go += red2[w][12 + jj][bb];
                    }
                    gi += bih[ja] + bhh[ja];
                    gf += bih[1024 + ja] + bhh[1024 + ja];
                    gg += bih[2048 + ja] + bhh[2048 + ja];
                    go += bih[3072 + ja] + bhh[3072 + ja];
                    int idx = ((ja >> 2) * 32 + bb) * 4 + (ja & 3);
                    float cn = sigmoidf_(gf) * cc[idx] + sigmoidf_(gi) * tanhf_(gg);
                    cc[idx] = cn;                      // block-local, cached
                    float hn = sigmoidf_(go) * tanhf_(cn);
                    stc4(&h[idx], hn);                 // cross-block: write-through
                    if (L1) {
                        stc4(&x2v[(size_t)(t & 1) * 32768 + idx], hn);
                    } else {
                        A.hs[(size_t)bb * 65536 + (size_t)t * 1024 + ja] = hn;  // read after kernel end
                    }
                }
            }
            gbar(A.bar, ++bcnt);
        }
    }
}

// ---------------- embedding gather into k4-interleaved layout ----------------
__global__ __launch_bounds__(256) void gather_embed(const int* __restrict__ seq,
                                                    const float* __restrict__ emb,
                                                    float* __restrict__ XT) {
    int t = blockIdx.x;
    const float4* emb4 = (const float4*)emb;
    float4* xt4 = (float4*)(XT + (size_t)t * 32768);
#pragma unroll 4
    for (int b = 0; b < 32; ++b) {
        int row = seq[b * 64 + t];
        float4 v = emb4[(size_t)row * 256 + threadIdx.x];
        xt4[threadIdx.x * 32 + b] = v;
    }
}

// ---------------- fp32 -> bf16 ----------------
__global__ __launch_bounds__(256) void f32_to_bf16(const float* __restrict__ in,
                                                   unsigned short* __restrict__ out, int n) {
    int i = (blockIdx.x * 256 + threadIdx.x) * 8;
    if (i + 7 < n) {
        float4 f0 = *(const float4*)(in + i);
        float4 f1 = *(const float4*)(in + i + 4);
        bf16x8 v;
        v[0] = (short)f2bf(f0.x); v[1] = (short)f2bf(f0.y);
        v[2] = (short)f2bf(f0.z); v[3] = (short)f2bf(f0.w);
        v[4] = (short)f2bf(f1.x); v[5] = (short)f2bf(f1.y);
        v[6] = (short)f2bf(f1.z); v[7] = (short)f2bf(f1.w);
        *(bf16x8*)(out + i) = v;
    }
}

// ---------------- output projection (bf16 MFMA, 128x128 tile) ----------------
__global__ __launch_bounds__(256) void out_proj(const unsigned short* __restrict__ hsb,
                                                const float* __restrict__ emb,
                                                const float* __restrict__ fcb,
                                                float* __restrict__ out) {
    __shared__ unsigned short Al[128 * 40];
    __shared__ unsigned short Bl[128 * 40];
    int tid = threadIdx.x;
    int n0 = blockIdx.x * 128;
    int m0 = blockIdx.y * 128;
    int wid = tid >> 6, l = tid & 63;
    int wm = wid >> 1, wn = wid & 1;
    int c16 = l & 15, kg = l >> 4;

    f32x4 acc[4][4];
#pragma unroll
    for (int i = 0; i < 4; i++)
#pragma unroll
        for (int j = 0; j < 4; j++) acc[i][j] = (f32x4){0.f, 0.f, 0.f, 0.f};

    for (int k0 = 0; k0 < 1024; k0 += 32) {
#pragma unroll
        for (int i = 0; i < 2; i++) {
            int id = i * 256 + tid;
            int r = id >> 2, ccc = id & 3;
            *(bf16x8*)&Al[r * 40 + ccc * 8] =
                *(const bf16x8*)(hsb + (size_t)(m0 + r) * 1024 + k0 + ccc * 8);
        }
#pragma unroll
        for (int i = 0; i < 2; i++) {
            int id = i * 256 + tid;
            int r = id >> 2, ccc = id & 3;
            const float* src = emb + (size_t)(n0 + r) * 1024 + k0 + ccc * 8;
            float4 f0 = *(const float4*)(src);
            float4 f1 = *(const float4*)(src + 4);
            bf16x8 v;
            v[0] = (short)f2bf(f0.x); v[1] = (short)f2bf(f0.y);
            v[2] = (short)f2bf(f0.z); v[3] = (short)f2bf(f0.w);
            v[4] = (short)f2bf(f1.x); v[5] = (short)f2bf(f1.y);
            v[6] = (short)f2bf(f1.z); v[7] = (short)f2bf(f1.w);
            *(bf16x8*)&Bl[r * 40 + ccc * 8] = v;
        }
        __syncthreads();

        bf16x8 afr[4], bfr[4];
#pragma unroll
        for (int i = 0; i < 4; i++)
            afr[i] = *(const bf16x8*)&Al[(wm * 64 + i * 16 + c16) * 40 + kg * 8];
#pragma unroll
        for (int j = 0; j < 4; j++)
            bfr[j] = *(const bf16x8*)&Bl[(wn * 64 + j * 16 + c16) * 40 + kg * 8];
#pragma unroll
        for (int i = 0; i < 4; i++)
#pragma unroll
            for (int j = 0; j < 4; j++)
                acc[i][j] = __builtin_amdgcn_mfma_f32_16x16x32_bf16(afr[i], bfr[j], acc[i][j], 0, 0, 0);
        __syncthreads();
    }

#pragma unroll
    for (int i = 0; i < 4; i++) {
        int row = m0 + wm * 64 + i * 16 + kg * 4;
#pragma unroll
        for (int j = 0; j < 4; j++) {
            int col = n0 + wn * 64 + j * 16 + c16;
            float fb = fcb[col];
#pragma unroll
            for (int r = 0; r < 4; r++)
                out[(size_t)(row + r) * 32000 + col] = acc[i][j][r] + fb;
        }
    }
}

// ---------------- host ----------------
extern "C" void kernel_launch(void* const* d_in, const int* in_sizes, int n_in,
                              void* d_out, int out_size, void* d_ws, size_t ws_size,
                              hipStream_t stream) {
    const int*   seq    = (const int*)d_in[0];
    const float* emb    = (const float*)d_in[2];
    const float* mog1_W = (const float*)d_in[3];
    const float* mog1_b = (const float*)d_in[4];
    const float* W_ih1  = (const float*)d_in[5];
    const float* W_hh1  = (const float*)d_in[6];
    const float* b_ih1  = (const float*)d_in[7];
    const float* b_hh1  = (const float*)d_in[8];
    const float* mog2_W = (const float*)d_in[9];
    const float* mog2_b = (const float*)d_in[10];
    const float* W_ih2  = (const float*)d_in[11];
    const float* W_hh2  = (const float*)d_in[12];
    const float* b_ih2  = (const float*)d_in[13];
    const float* b_hh2  = (const float*)d_in[14];
    const float* fc_b   = (const float*)d_in[15];

    char* ws = (char*)d_ws;
    float* XT = (float*)ws;                                  // 8 MB
    float* st = (float*)(ws + 8388608);                      // 1 MB
    unsigned* bar = (unsigned*)(ws + 9437184);               // 16 KB (64 padded counters + gen)
    unsigned short* hsb = (unsigned short*)(ws + 9453568);   // 4 MB

    float* out0 = (float*)d_out;
    float* hs   = out0 + 65536000LL;

    hipMemsetAsync(st, 0, 524288, stream);
    hipMemsetAsync(bar, 0, 16384, stream);

    gather_embed<<<64, 256, 0, stream>>>(seq, emb, XT);

    RArgs a;
    a.m1W = mog1_W; a.m1b = mog1_b;
    a.Wih1 = W_ih1; a.Whh1 = W_hh1; a.bih1 = b_ih1; a.bhh1 = b_hh1;
    a.m2W = mog2_W; a.m2b = mog2_b;
    a.Wih2 = W_ih2; a.Whh2 = W_hh2; a.bih2 = b_ih2; a.bhh2 = b_hh2;
    a.XT = XT; a.st = st; a.hs = hs; a.bar = bar;

    reck<<<512, 256, 0, stream>>>(a);

    f32_to_bf16<<<1024, 256, 0, stream>>>(hs, hsb, 2097152);
    out_proj<<<dim3(250, 16), 256, 0, stream>>>(hsb, emb, fc_b, out0);
}

// Round 7
// 6320.423 us; speedup vs baseline: 1.0774x; 1.0774x over previous
//
#include <hip/hip_runtime.h>

typedef short bf16x8 __attribute__((ext_vector_type(8)));
typedef float f32x4 __attribute__((ext_vector_type(4)));
typedef unsigned int u32;
typedef u32 u32x4 __attribute__((ext_vector_type(4)));
typedef unsigned short u16;

static __device__ __forceinline__ unsigned short f2bf(float f) {
    unsigned int u = __float_as_uint(f);
    unsigned int r = (u + 0x7fffu + ((u >> 16) & 1u)) >> 16;
    return (unsigned short)r;
}
static __device__ __forceinline__ float sigmoidf_(float x) {
    return 1.0f / (1.0f + __expf(-x));
}
static __device__ __forceinline__ float tanhf_(float x) {
    return 2.0f / (1.0f + __expf(-2.0f * x)) - 1.0f;
}

// truncation-split packing: fp32 -> (hi bf16, lo bf16), x ~= hi + lo, residual ~2^-18
static __device__ __forceinline__ u32 pkhi(float a, float b) {
    return (__float_as_uint(a) >> 16) | (__float_as_uint(b) & 0xffff0000u);
}
static __device__ __forceinline__ u32 pklo(float a, float b) {
    float la = a - __uint_as_float(__float_as_uint(a) & 0xffff0000u);
    float lb = b - __uint_as_float(__float_as_uint(b) & 0xffff0000u);
    return (__float_as_uint(la) >> 16) | (__float_as_uint(lb) & 0xffff0000u);
}
static __device__ __forceinline__ bf16x8 mkfrag(u32 a, u32 b, u32 c, u32 d) {
    u32x4 v = {a, b, c, d};
    return __builtin_bit_cast(bf16x8, v);
}

// coherent (agent-scope, write-through) stores for cross-block activations
static __device__ __forceinline__ void stc4(float* p, float v) {
    __hip_atomic_store(p, v, __ATOMIC_RELAXED, __HIP_MEMORY_SCOPE_AGENT);
}
static __device__ __forceinline__ void stc2(u16* p, u16 v) {
    __hip_atomic_store(p, v, __ATOMIC_RELAXED, __HIP_MEMORY_SCOPE_AGENT);
}

// async global -> LDS, 16 B/lane; LDS base wave-uniform, global addr per-lane
static __device__ __forceinline__ void dma16(const float* g, float* l) {
    __builtin_amdgcn_global_load_lds((const __attribute__((address_space(1))) void*)g,
                                     (__attribute__((address_space(3))) void*)l, 16, 0, 0);
}

// ---------------- grid barrier: self-deciding distributed counters + 1 acquire fence ----
// bar: cnt[i] at bar[i*32] (i<64, 128B apart, monotonic); 256 blocks, 4 per counter.
static __device__ __forceinline__ void gbar(u32* bar, u32 target) {
    asm volatile("s_waitcnt vmcnt(0) lgkmcnt(0)" ::: "memory");
    __builtin_amdgcn_s_barrier();
    const int tid = threadIdx.x;
    if (tid == 0) {
        __hip_atomic_fetch_add(bar + ((blockIdx.x & 63) << 5), 1u,
                               __ATOMIC_RELAXED, __HIP_MEMORY_SCOPE_AGENT);
    }
    if (tid < 64) {
        const u32 tgt = target << 8;   // 256 * target
        for (;;) {
            u32 v = __hip_atomic_load(bar + (tid << 5), __ATOMIC_RELAXED,
                                      __HIP_MEMORY_SCOPE_AGENT);
            v += __shfl_xor(v, 1);
            v += __shfl_xor(v, 2);
            v += __shfl_xor(v, 4);
            v += __shfl_xor(v, 8);
            v += __shfl_xor(v, 16);
            v += __shfl_xor(v, 32);
            if (v >= tgt) break;
            __builtin_amdgcn_s_sleep(1);
        }
        if (tid == 0) __builtin_amdgcn_fence(__ATOMIC_ACQUIRE, "agent");
    }
    __builtin_amdgcn_s_barrier();
    asm volatile("" ::: "memory");
}

// ---------------- weight chunk staging ----------------
// mog chunk: 16 rows x 512 k fp32 = 32KB. LDS float idx = oct*128 + row*8 + h*4
static __device__ __forceinline__ void stage_mog(const float* W, int j0, int kb,
                                                 float* lbuf, int lane, int wv) {
#pragma unroll
    for (int i = 0; i < 8; ++i) {
        int og = wv * 8 + i;
        int oct = og * 2 + (lane >> 5);
        int row = (lane >> 1) & 15;
        const float* src = W + (size_t)(j0 + row) * 1024 + kb + oct * 8 + (lane & 1) * 4;
        dma16(src, lbuf + og * 256);
    }
}
// lstm chunk: 64 rows (4 gates x 16 cells) x 128 k fp32 = 32KB.
// LDS float idx = oct*512 + row*8 + h*4 ; global row = (rowc>>4)*1024 + j0c + (rowc&15)
static __device__ __forceinline__ void stage_lstm(const float* Wside, int j0c, int kb,
                                                  float* lbuf, int lane, int wv) {
#pragma unroll
    for (int i = 0; i < 8; ++i) {
        int id = wv * 8 + i;          // 0..31
        int og = id >> 1, rh = id & 1;
        int rowc = rh * 32 + (lane >> 1);
        int grow = (rowc >> 4) * 1024 + j0c + (rowc & 15);
        const float* src = Wside + (size_t)grow * 1024 + kb + og * 8 + (lane & 1) * 4;
        dma16(src, lbuf + og * 512 + rh * 256);
    }
}

// ---------------- MFMA chunk compute ----------------
// mog: wave wv takes K128 of the chunk (4 ktiles); W rows = lane&15 of j-tile.
static __device__ __forceinline__ void mog_chunk(const float* lbuf, const u16* aH, const u16* aL,
                                                 int kb, int lane, int wv,
                                                 f32x4& a0, f32x4& a1) {
#pragma unroll
    for (int kt = 0; kt < 4; ++kt) {
        int octc = wv * 16 + kt * 4 + (lane >> 4);
        const float* wp = lbuf + octc * 128 + (lane & 15) * 8;
        f32x4 w0 = *(const f32x4*)wp;
        f32x4 w1 = *(const f32x4*)(wp + 4);
        bf16x8 whi = mkfrag(pkhi(w0.x, w0.y), pkhi(w0.z, w0.w), pkhi(w1.x, w1.y), pkhi(w1.z, w1.w));
        bf16x8 wlo = mkfrag(pklo(w0.x, w0.y), pklo(w0.z, w0.w), pklo(w1.x, w1.y), pklo(w1.z, w1.w));
        size_t octg = (size_t)(kb >> 3) + octc;
        bf16x8 ah0 = *(const bf16x8*)(aH + (octg * 32 + (lane & 15)) * 8);
        bf16x8 ah1 = *(const bf16x8*)(aH + (octg * 32 + 16 + (lane & 15)) * 8);
        bf16x8 al0 = *(const bf16x8*)(aL + (octg * 32 + (lane & 15)) * 8);
        bf16x8 al1 = *(const bf16x8*)(aL + (octg * 32 + 16 + (lane & 15)) * 8);
        a0 = __builtin_amdgcn_mfma_f32_16x16x32_bf16(ah0, whi, a0, 0, 0, 0);
        a0 = __builtin_amdgcn_mfma_f32_16x16x32_bf16(al0, whi, a0, 0, 0, 0);
        a0 = __builtin_amdgcn_mfma_f32_16x16x32_bf16(ah0, wlo, a0, 0, 0, 0);
        a1 = __builtin_amdgcn_mfma_f32_16x16x32_bf16(ah1, whi, a1, 0, 0, 0);
        a1 = __builtin_amdgcn_mfma_f32_16x16x32_bf16(al1, whi, a1, 0, 0, 0);
        a1 = __builtin_amdgcn_mfma_f32_16x16x32_bf16(ah1, wlo, a1, 0, 0, 0);
    }
}
// lstm: wave wv = gate wv; full K per wave, 4 ktiles per chunk.
static __device__ __forceinline__ void lstm_chunk(const float* lbuf, const u16* aH, const u16* aL,
                                                  int octab, int lane, int wv,
                                                  f32x4& a0, f32x4& a1) {
#pragma unroll
    for (int kt = 0; kt < 4; ++kt) {
        int octc = kt * 4 + (lane >> 4);
        const float* wp = lbuf + octc * 512 + (wv * 16 + (lane & 15)) * 8;
        f32x4 w0 = *(const f32x4*)wp;
        f32x4 w1 = *(const f32x4*)(wp + 4);
        bf16x8 whi = mkfrag(pkhi(w0.x, w0.y), pkhi(w0.z, w0.w), pkhi(w1.x, w1.y), pkhi(w1.z, w1.w));
        bf16x8 wlo = mkfrag(pklo(w0.x, w0.y), pklo(w0.z, w0.w), pklo(w1.x, w1.y), pklo(w1.z, w1.w));
        size_t octa = (size_t)octab + octc;
        bf16x8 ah0 = *(const bf16x8*)(aH + (octa * 32 + (lane & 15)) * 8);
        bf16x8 ah1 = *(const bf16x8*)(aH + (octa * 32 + 16 + (lane & 15)) * 8);
        bf16x8 al0 = *(const bf16x8*)(aL + (octa * 32 + (lane & 15)) * 8);
        bf16x8 al1 = *(const bf16x8*)(aL + (octa * 32 + 16 + (lane & 15)) * 8);
        a0 = __builtin_amdgcn_mfma_f32_16x16x32_bf16(ah0, whi, a0, 0, 0, 0);
        a0 = __builtin_amdgcn_mfma_f32_16x16x32_bf16(al0, whi, a0, 0, 0, 0);
        a0 = __builtin_amdgcn_mfma_f32_16x16x32_bf16(ah0, wlo, a0, 0, 0, 0);
        a1 = __builtin_amdgcn_mfma_f32_16x16x32_bf16(ah1, whi, a1, 0, 0, 0);
        a1 = __builtin_amdgcn_mfma_f32_16x16x32_bf16(al1, whi, a1, 0, 0, 0);
        a1 = __builtin_amdgcn_mfma_f32_16x16x32_bf16(ah1, wlo, a1, 0, 0, 0);
    }
}

// ---------------- persistent recurrence kernel ----------------
struct RArgs {
    const float *m1W, *m1b, *Wih1, *Whh1, *bih1, *bhh1;
    const float *m2W, *m2b, *Wih2, *Whh2, *bih2, *bhh2;
    float *XTF;
    u16 *XTH, *XTL;
    float* stF;
    u16* stH;
    float* hs;
    u32* bar;
};

__global__ __launch_bounds__(256) void reck(RArgs A) {
    __shared__ float buf[2][8192];      // 2 x 32KB weight chunks
    __shared__ float red[4][32][16];    // 8KB reduction scratch

    const int tid = threadIdx.x, lane = tid & 63, wv = tid >> 6;
    const int blk = blockIdx.x;
    const int layer = blk >> 7;         // 0: L1, 1: L2
    const int g = blk & 127;
    const bool isMog = g < 64;
    const int jb = (g & 63) * 16;       // j0 (mog) or cell-base (lstm)

    const float* mW  = layer ? A.m2W : A.m1W;
    const float* mb_ = layer ? A.m2b : A.m1b;
    const float* Wih = layer ? A.Wih2 : A.Wih1;
    const float* Whh = layer ? A.Whh2 : A.Whh1;
    const float* bih = layer ? A.bih2 : A.bih1;
    const float* bhh = layer ? A.bhh2 : A.bhh1;

    float* hF  = A.stF + layer * 32768;
    float* hmF = A.stF + 65536 + layer * 32768;
    float* cS  = A.stF + 131072 + layer * 32768;
    float* rFb = A.stF + 196608;        // ring fp32 [2][32768]
    u16* hH  = A.stH + layer * 32768;
    u16* hmH = A.stH + 65536 + layer * 32768;
    u16* rHb = A.stH + 131072;          // ring hi [2]
    u16* hL  = A.stH + 196608 + layer * 32768;
    u16* hmL = A.stH + 262144 + layer * 32768;
    u16* rLb = A.stH + 327680;          // ring lo [2]

    u32 bcnt = 0;

    if (isMog) stage_mog(mW, jb, 0, buf[0], lane, wv);   // prologue: ph0 chunk0

    for (int s = 0; s <= 64; ++s) {
        const bool act = layer ? (s > 0) : (s < 64);
        const int t = layer ? s - 1 : s;
        const int tt = act ? t : 0;
        const int rb = tt & 1;          // L2 reads ring[t&1]; L1 writes ring[s&1]

        float* xF; u16 *xH, *xL;
        if (layer == 0) {
            xF = A.XTF + (size_t)tt * 32768;
            xH = A.XTH + (size_t)tt * 32768;
            xL = A.XTL + (size_t)tt * 32768;
        } else {
            xF = rFb + rb * 32768;
            xH = rHb + rb * 32768;
            xL = rLb + rb * 32768;
        }

        f32x4 La0 = {0.f, 0.f, 0.f, 0.f}, La1 = {0.f, 0.f, 0.f, 0.f};  // lstm accs (persist over gbar)

        if (!isMog && act) {            // prestage lstm chunks 0,1 (Whh side, weights static)
            stage_lstm(Whh, jb, 0, buf[0], lane, wv);
            stage_lstm(Whh, jb, 128, buf[1], lane, wv);
        }

        for (int ph = 0; ph < 5; ++ph) {
            if (isMog) {
                const float* Wp = mW + (size_t)ph * 1048576;
                stage_mog(Wp, jb, 512, buf[1], lane, wv);       // chunk1 of this phase
                const u16 *gHp, *gLp; const float* srcF; float* dF; u16 *dH, *dL;
                switch (ph) {
                    case 0:  gHp = hH;  gLp = hL;  srcF = xF;  dF = xF;  dH = xH;  dL = xL;  break;
                    case 1:  gHp = xH;  gLp = xL;  srcF = hF;  dF = hmF; dH = hmH; dL = hmL; break;
                    case 2:  gHp = hmH; gLp = hmL; srcF = xF;  dF = xF;  dH = xH;  dL = xL;  break;
                    case 3:  gHp = xH;  gLp = xL;  srcF = hmF; dF = hmF; dH = hmH; dL = hmL; break;
                    default: gHp = hmH; gLp = hmL; srcF = xF;  dF = xF;  dH = xH;  dL = xL;  break;
                }
                f32x4 a0 = {0.f, 0.f, 0.f, 0.f}, a1 = {0.f, 0.f, 0.f, 0.f};
                if (act) mog_chunk(buf[0], gHp, gLp, 0, lane, wv, a0, a1);
                asm volatile("s_waitcnt vmcnt(0)" ::: "memory");
                __builtin_amdgcn_s_barrier();
                stage_mog(mW + (size_t)((ph + 1) % 5) * 1048576, jb, 0, buf[0], lane, wv);
                if (act) {
                    mog_chunk(buf[1], gHp, gLp, 512, lane, wv, a0, a1);
#pragma unroll
                    for (int mh = 0; mh < 2; ++mh) {
                        f32x4 av = mh ? a1 : a0;
#pragma unroll
                        for (int r = 0; r < 4; ++r)
                            red[wv][mh * 16 + (lane >> 4) * 4 + r][lane & 15] = av[r];
                    }
                    __syncthreads();
#pragma unroll
                    for (int uu = 0; uu < 2; ++uu) {
                        int u = tid + uu * 256;
                        int jj = u & 15, bb = u >> 4;
                        float sv = red[0][bb][jj] + red[1][bb][jj] + red[2][bb][jj] + red[3][bb][jj];
                        int d = jb + jj;
                        sv += mb_[ph * 1024 + d];
                        float gate = 2.0f * sigmoidf_(sv);
                        size_t pidx = ((size_t)(d >> 3) * 32 + bb) * 8 + (d & 7);
                        float val = gate * srcF[pidx];
                        stc4(dF + pidx, val);
                        u32 uv = __float_as_uint(val);
                        stc2(dH + pidx, (u16)(uv >> 16));
                        float lov = val - __uint_as_float(uv & 0xffff0000u);
                        stc2(dL + pidx, (u16)(__float_as_uint(lov) >> 16));
                    }
                }
            } else if (act && ph == 4) {
                // lstm blocks: compute Whh side (chunks 0..7) overlapping mog ph4
                for (int c = 0; c < 8; ++c) {
                    lstm_chunk(buf[c & 1], hmH, hmL, c * 16, lane, wv, La0, La1);
                    asm volatile("s_waitcnt vmcnt(0)" ::: "memory");
                    __builtin_amdgcn_s_barrier();
                    int cn = c + 2;
                    const float* Ws = (cn < 8) ? Whh : Wih;
                    stage_lstm(Ws, jb, (cn & 7) * 128, buf[cn & 1], lane, wv);
                }
            }
            gbar(A.bar, ++bcnt);
        }

        // ---------------- LSTM x-side + gates ----------------
        if (!isMog && act) {
            for (int c = 8; c < 16; ++c) {
                lstm_chunk(buf[c & 1], xH, xL, (c & 7) * 16, lane, wv, La0, La1);
                asm volatile("s_waitcnt vmcnt(0)" ::: "memory");
                __builtin_amdgcn_s_barrier();
                if (c + 2 < 16) stage_lstm(Wih, jb, ((c + 2) & 7) * 128, buf[c & 1], lane, wv);
            }
#pragma unroll
            for (int mh = 0; mh < 2; ++mh) {
                f32x4 av = mh ? La1 : La0;
#pragma unroll
                for (int r = 0; r < 4; ++r)
                    red[wv][mh * 16 + (lane >> 4) * 4 + r][lane & 15] = av[r];
            }
            __syncthreads();
#pragma unroll
            for (int uu = 0; uu < 2; ++uu) {
                int u = tid + uu * 256;
                int cell = u & 15, bb = u >> 4;
                int d = jb + cell;
                float gi = red[0][bb][cell] + bih[d] + bhh[d];
                float gf = red[1][bb][cell] + bih[1024 + d] + bhh[1024 + d];
                float gg = red[2][bb][cell] + bih[2048 + d] + bhh[2048 + d];
                float go = red[3][bb][cell] + bih[3072 + d] + bhh[3072 + d];
                int cidx = d * 32 + bb;
                float cn = sigmoidf_(gf) * cS[cidx] + sigmoidf_(gi) * tanhf_(gg);
                cS[cidx] = cn;
                float hn = sigmoidf_(go) * tanhf_(cn);
                size_t pidx = ((size_t)(d >> 3) * 32 + bb) * 8 + (d & 7);
                u32 uv = __float_as_uint(hn);
                u16 hhi = (u16)(uv >> 16);
                float lov = hn - __uint_as_float(uv & 0xffff0000u);
                u16 hlo = (u16)(__float_as_uint(lov) >> 16);
                stc4(hF + pidx, hn);
                stc2(hH + pidx, hhi);
                stc2(hL + pidx, hlo);
                if (layer == 0) {
                    int wb = s & 1;
                    stc4(rFb + wb * 32768 + pidx, hn);
                    stc2(rHb + wb * 32768 + pidx, hhi);
                    stc2(rLb + wb * 32768 + pidx, hlo);
                } else {
                    A.hs[(size_t)bb * 65536 + (size_t)t * 1024 + d] = hn;
                }
            }
        }
        gbar(A.bar, ++bcnt);
    }
}

// ---------------- embedding gather into fp32 + hi/lo bf16 planes ----------------
__global__ __launch_bounds__(256) void gather_embed(const int* __restrict__ seq,
                                                    const float* __restrict__ emb,
                                                    float* __restrict__ XTF,
                                                    u16* __restrict__ XTH,
                                                    u16* __restrict__ XTL) {
    int t = blockIdx.x;
#pragma unroll 4
    for (int i = 0; i < 16; ++i) {
        int u = i * 256 + threadIdx.x;   // 0..4095 : (oct, b)
        int oct = u >> 5, b = u & 31;
        int row = seq[b * 64 + t];
        const float* sp = emb + (size_t)row * 1024 + oct * 8;
        float4 f0 = *(const float4*)sp;
        float4 f1 = *(const float4*)(sp + 4);
        size_t base = (size_t)t * 32768 + ((size_t)oct * 32 + b) * 8;
        *(float4*)(XTF + base) = f0;
        *(float4*)(XTF + base + 4) = f1;
        u32x4 hi = {pkhi(f0.x, f0.y), pkhi(f0.z, f0.w), pkhi(f1.x, f1.y), pkhi(f1.z, f1.w)};
        u32x4 lo = {pklo(f0.x, f0.y), pklo(f0.z, f0.w), pklo(f1.x, f1.y), pklo(f1.z, f1.w)};
        *(u32x4*)(XTH + base) = hi;
        *(u32x4*)(XTL + base) = lo;
    }
}

// ---------------- fp32 -> bf16 (RNE, for projection A) ----------------
__global__ __launch_bounds__(256) void f32_to_bf16(const float* __restrict__ in,
                                                   unsigned short* __restrict__ out, int n) {
    int i = (blockIdx.x * 256 + threadIdx.x) * 8;
    if (i + 7 < n) {
        float4 f0 = *(const float4*)(in + i);
        float4 f1 = *(const float4*)(in + i + 4);
        bf16x8 v;
        v[0] = (short)f2bf(f0.x); v[1] = (short)f2bf(f0.y);
        v[2] = (short)f2bf(f0.z); v[3] = (short)f2bf(f0.w);
        v[4] = (short)f2bf(f1.x); v[5] = (short)f2bf(f1.y);
        v[6] = (short)f2bf(f1.z); v[7] = (short)f2bf(f1.w);
        *(bf16x8*)(out + i) = v;
    }
}

// ---------------- output projection (bf16 MFMA, 128x128 tile) ----------------
__global__ __launch_bounds__(256) void out_proj(const unsigned short* __restrict__ hsb,
                                                const float* __restrict__ emb,
                                                const float* __restrict__ fcb,
                                                float* __restrict__ out) {
    __shared__ unsigned short Al[128 * 40];
    __shared__ unsigned short Bl[128 * 40];
    int tid = threadIdx.x;
    int n0 = blockIdx.x * 128;
    int m0 = blockIdx.y * 128;
    int wid = tid >> 6, l = tid & 63;
    int wm = wid >> 1, wn = wid & 1;
    int c16 = l & 15, kg = l >> 4;

    f32x4 acc[4][4];
#pragma unroll
    for (int i = 0; i < 4; i++)
#pragma unroll
        for (int j = 0; j < 4; j++) acc[i][j] = (f32x4){0.f, 0.f, 0.f, 0.f};

    for (int k0 = 0; k0 < 1024; k0 += 32) {
#pragma unroll
        for (int i = 0; i < 2; i++) {
            int id = i * 256 + tid;
            int r = id >> 2, ccc = id & 3;
            *(bf16x8*)&Al[r * 40 + ccc * 8] =
                *(const bf16x8*)(hsb + (size_t)(m0 + r) * 1024 + k0 + ccc * 8);
        }
#pragma unroll
        for (int i = 0; i < 2; i++) {
            int id = i * 256 + tid;
            int r = id >> 2, ccc = id & 3;
            const float* src = emb + (size_t)(n0 + r) * 1024 + k0 + ccc * 8;
            float4 f0 = *(const float4*)(src);
            float4 f1 = *(const float4*)(src + 4);
            bf16x8 v;
            v[0] = (short)f2bf(f0.x); v[1] = (short)f2bf(f0.y);
            v[2] = (short)f2bf(f0.z); v[3] = (short)f2bf(f0.w);
            v[4] = (short)f2bf(f1.x); v[5] = (short)f2bf(f1.y);
            v[6] = (short)f2bf(f1.z); v[7] = (short)f2bf(f1.w);
            *(bf16x8*)&Bl[r * 40 + ccc * 8] = v;
        }
        __syncthreads();

        bf16x8 afr[4], bfr[4];
#pragma unroll
        for (int i = 0; i < 4; i++)
            afr[i] = *(const bf16x8*)&Al[(wm * 64 + i * 16 + c16) * 40 + kg * 8];
#pragma unroll
        for (int j = 0; j < 4; j++)
            bfr[j] = *(const bf16x8*)&Bl[(wn * 64 + j * 16 + c16) * 40 + kg * 8];
#pragma unroll
        for (int i = 0; i < 4; i++)
#pragma unroll
            for (int j = 0; j < 4; j++)
                acc[i][j] = __builtin_amdgcn_mfma_f32_16x16x32_bf16(afr[i], bfr[j], acc[i][j], 0, 0, 0);
        __syncthreads();
    }

#pragma unroll
    for (int i = 0; i < 4; i++) {
        int row = m0 + wm * 64 + i * 16 + kg * 4;
#pragma unroll
        for (int j = 0; j < 4; j++) {
            int col = n0 + wn * 64 + j * 16 + c16;
            float fb = fcb[col];
#pragma unroll
            for (int r = 0; r < 4; r++)
                out[(size_t)(row + r) * 32000 + col] = acc[i][j][r] + fb;
        }
    }
}

// ---------------- host ----------------
extern "C" void kernel_launch(void* const* d_in, const int* in_sizes, int n_in,
                              void* d_out, int out_size, void* d_ws, size_t ws_size,
                              hipStream_t stream) {
    const int*   seq    = (const int*)d_in[0];
    const float* emb    = (const float*)d_in[2];
    const float* mog1_W = (const float*)d_in[3];
    const float* mog1_b = (const float*)d_in[4];
    const float* W_ih1  = (const float*)d_in[5];
    const float* W_hh1  = (const float*)d_in[6];
    const float* b_ih1  = (const float*)d_in[7];
    const float* b_hh1  = (const float*)d_in[8];
    const float* mog2_W = (const float*)d_in[9];
    const float* mog2_b = (const float*)d_in[10];
    const float* W_ih2  = (const float*)d_in[11];
    const float* W_hh2  = (const float*)d_in[12];
    const float* b_ih2  = (const float*)d_in[13];
    const float* b_hh2  = (const float*)d_in[14];
    const float* fc_b   = (const float*)d_in[15];

    char* ws = (char*)d_ws;
    float* XTF = (float*)ws;                                  // 8 MB
    u16*   XTH = (u16*)(ws + 8388608);                        // 4 MB
    u16*   XTL = (u16*)(ws + 12582912);                       // 4 MB
    float* stF = (float*)(ws + 16777216);                     // 1 MB  (h,hm,c,ring fp32)
    u16*   stH = (u16*)(ws + 17825792);                       // 768 KB (hi/lo planes)
    u32*   bar = (u32*)(ws + 18874368);                       // 16 KB
    unsigned short* hsb = (unsigned short*)(ws + 18890752);   // 4 MB

    float* out0 = (float*)d_out;
    float* hs   = out0 + 65536000LL;

    hipMemsetAsync(stF, 0, 1835008, stream);   // stF (1MB) + stH (768KB), contiguous
    hipMemsetAsync(bar, 0, 16384, stream);

    gather_embed<<<64, 256, 0, stream>>>(seq, emb, XTF, XTH, XTL);

    RArgs a;
    a.m1W = mog1_W; a.m1b = mog1_b;
    a.Wih1 = W_ih1; a.Whh1 = W_hh1; a.bih1 = b_ih1; a.bhh1 = b_hh1;
    a.m2W = mog2_W; a.m2b = mog2_b;
    a.Wih2 = W_ih2; a.Whh2 = W_hh2; a.bih2 = b_ih2; a.bhh2 = b_hh2;
    a.XTF = XTF; a.XTH = XTH; a.XTL = XTL;
    a.stF = stF; a.stH = stH; a.hs = hs; a.bar = bar;

    reck<<<256, 256, 0, stream>>>(a);

    f32_to_bf16<<<1024, 256, 0, stream>>>(hs, hsb, 2097152);
    out_proj<<<dim3(250, 16), 256, 0, stream>>>(hsb, emb, fc_b, out0);
}

// Round 8
// 4820.669 us; speedup vs baseline: 1.4126x; 1.3111x over previous
//
#include <hip/hip_runtime.h>

typedef short bf16x8 __attribute__((ext_vector_type(8)));
typedef float f32x4 __attribute__((ext_vector_type(4)));
typedef unsigned int u32;
typedef u32 u32x4 __attribute__((ext_vector_type(4)));
typedef unsigned short u16;
typedef unsigned long long u64;

static __device__ __forceinline__ unsigned short f2bf(float f) {
    unsigned int u = __float_as_uint(f);
    unsigned int r = (u + 0x7fffu + ((u >> 16) & 1u)) >> 16;
    return (unsigned short)r;
}
static __device__ __forceinline__ float sigmoidf_(float x) {
    return 1.0f / (1.0f + __expf(-x));
}
static __device__ __forceinline__ float tanhf_(float x) {
    return 2.0f / (1.0f + __expf(-2.0f * x)) - 1.0f;
}

// truncation-split packing: fp32 -> (hi bf16, lo bf16), x ~= hi + lo
static __device__ __forceinline__ u32 pkhi(float a, float b) {
    return (__float_as_uint(a) >> 16) | (__float_as_uint(b) & 0xffff0000u);
}
static __device__ __forceinline__ u32 pklo(float a, float b) {
    float la = a - __uint_as_float(__float_as_uint(a) & 0xffff0000u);
    float lb = b - __uint_as_float(__float_as_uint(b) & 0xffff0000u);
    return (__float_as_uint(la) >> 16) | (__float_as_uint(lb) & 0xffff0000u);
}
static __device__ __forceinline__ bf16x8 mkfrag(u32 a, u32 b, u32 c, u32 d) {
    u32x4 v = {a, b, c, d};
    return __builtin_bit_cast(bf16x8, v);
}

// ---- sc1 coherent activation access (R5 scheme: no fences anywhere) ----
static __device__ __forceinline__ bf16x8 ldA(const u16* p) {
    u64 a = __hip_atomic_load((const u64*)p, __ATOMIC_RELAXED, __HIP_MEMORY_SCOPE_AGENT);
    u64 b = __hip_atomic_load((const u64*)(p + 4), __ATOMIC_RELAXED, __HIP_MEMORY_SCOPE_AGENT);
    union { u64 q[2]; bf16x8 v; } u;
    u.q[0] = a; u.q[1] = b;
    return u.v;
}
static __device__ __forceinline__ float ldc4(const float* p) {
    return __hip_atomic_load(p, __ATOMIC_RELAXED, __HIP_MEMORY_SCOPE_AGENT);
}
static __device__ __forceinline__ void stc4(float* p, float v) {
    __hip_atomic_store(p, v, __ATOMIC_RELAXED, __HIP_MEMORY_SCOPE_AGENT);
}
static __device__ __forceinline__ void stc2(u16* p, u16 v) {
    __hip_atomic_store(p, v, __ATOMIC_RELAXED, __HIP_MEMORY_SCOPE_AGENT);
}

// async global -> LDS, 16 B/lane
static __device__ __forceinline__ void dma16(const float* g, float* l) {
    __builtin_amdgcn_global_load_lds((const __attribute__((address_space(1))) void*)g,
                                     (__attribute__((address_space(3))) void*)l, 16, 0, 0);
}

// ---- planes layout: element (d,b) at ((d>>3)*32 + b)*8 + (d&7) ----

// ---------------- grid barrier, split arrive/wait; fence-free (sc1 data) ----------------
static __device__ __forceinline__ void gbar_arrive(u32* bar) {
    asm volatile("s_waitcnt vmcnt(0) lgkmcnt(0)" ::: "memory");
    __builtin_amdgcn_s_barrier();
    if (threadIdx.x == 0)
        __hip_atomic_fetch_add(bar + ((blockIdx.x & 63) << 5), 1u,
                               __ATOMIC_RELAXED, __HIP_MEMORY_SCOPE_AGENT);
}
static __device__ __forceinline__ void gbar_wait(u32* bar, u32 target) {
    if (threadIdx.x < 64) {
        const u32 tgt = target << 8;   // 256 blocks
        for (;;) {
            u32 v = __hip_atomic_load(bar + (threadIdx.x << 5), __ATOMIC_RELAXED,
                                      __HIP_MEMORY_SCOPE_AGENT);
            v += __shfl_xor(v, 1);
            v += __shfl_xor(v, 2);
            v += __shfl_xor(v, 4);
            v += __shfl_xor(v, 8);
            v += __shfl_xor(v, 16);
            v += __shfl_xor(v, 32);
            if (v >= tgt) break;
            __builtin_amdgcn_s_sleep(1);
        }
    }
    __builtin_amdgcn_s_barrier();
    asm volatile("" ::: "memory");
}

// ---------------- weight staging: SELF-STAGED (wave stages exactly what it reads) ------
// mog: 16 rows x 1024k fp32 = 64KB. LDS float idx = oct*128 + row*8 + half*4.
// wave wv covers octs [32wv, 32wv+32) = K [256wv, 256wv+256).
static __device__ __forceinline__ void stage_mogF(const float* W, int jb, float* lbuf,
                                                  int lane, int wv) {
    int oct2 = lane >> 5, row = (lane >> 1) & 15, half = lane & 1;
#pragma unroll
    for (int i = 0; i < 16; ++i) {
        int og = wv * 16 + i;
        const float* src = W + (size_t)(jb + row) * 1024 + (og * 2 + oct2) * 8 + half * 4;
        dma16(src, lbuf + og * 256);
    }
}
// lstm chunk: 64 rows (4 gates x 16 cells) x 256k = 64KB. idx = octl*512 + rowc*8 + half*4.
// wave wv covers octl [8wv, 8wv+8) = chunk-K [64wv, 64wv+64).
static __device__ __forceinline__ void stage_lstmF(const float* Ws, int jb, int kb,
                                                   float* lbuf, int lane, int wv) {
    int row = lane >> 1, half = lane & 1;
#pragma unroll
    for (int i = 0; i < 16; ++i) {
        int octl = wv * 8 + (i >> 1);
        int rh = i & 1;
        int rowc = rh * 32 + row;
        int grow = (rowc >> 4) * 1024 + jb + (rowc & 15);
        const float* src = Ws + (size_t)grow * 1024 + kb + octl * 8 + half * 4;
        dma16(src, lbuf + octl * 512 + rh * 256);
    }
}

// ---------------- lstm chunk compute pieces ----------------
static __device__ __forceinline__ void lstm_acts(const u16* aH, const u16* aL, int kb,
                                                 int lane, int wv, bf16x8 fr[8]) {
    const int col = lane & 15, kq4 = lane >> 4;
#pragma unroll
    for (int ktl = 0; ktl < 2; ++ktl) {
        int octl = wv * 8 + ktl * 4 + kq4;
        size_t octa = (size_t)(kb >> 3) + octl;
        const u16* pH = aH + (octa * 32 + col) * 8;
        const u16* pL = aL + (octa * 32 + col) * 8;
        fr[ktl * 4 + 0] = ldA(pH);
        fr[ktl * 4 + 1] = ldA(pH + 128);
        fr[ktl * 4 + 2] = ldA(pL);
        fr[ktl * 4 + 3] = ldA(pL + 128);
    }
}
static __device__ __forceinline__ void lstm_mfma(const float* lbuf, const bf16x8 fr[8],
                                                 int lane, int wv, f32x4 (&acc)[4][2]) {
    const int col = lane & 15, kq4 = lane >> 4;
#pragma unroll
    for (int ktl = 0; ktl < 2; ++ktl) {
        int octl = wv * 8 + ktl * 4 + kq4;
        const float* wbase = lbuf + octl * 512;
        bf16x8 ah0 = fr[ktl * 4 + 0], ah1 = fr[ktl * 4 + 1];
        bf16x8 al0 = fr[ktl * 4 + 2], al1 = fr[ktl * 4 + 3];
#pragma unroll
        for (int rt = 0; rt < 4; ++rt) {
            const float* wp = wbase + (rt * 16 + col) * 8;
            f32x4 w0 = *(const f32x4*)wp, w1 = *(const f32x4*)(wp + 4);
            bf16x8 whi = mkfrag(pkhi(w0.x, w0.y), pkhi(w0.z, w0.w),
                                pkhi(w1.x, w1.y), pkhi(w1.z, w1.w));
            bf16x8 wlo = mkfrag(pklo(w0.x, w0.y), pklo(w0.z, w0.w),
                                pklo(w1.x, w1.y), pklo(w1.z, w1.w));
            acc[rt][0] = __builtin_amdgcn_mfma_f32_16x16x32_bf16(ah0, whi, acc[rt][0], 0, 0, 0);
            acc[rt][0] = __builtin_amdgcn_mfma_f32_16x16x32_bf16(al0, whi, acc[rt][0], 0, 0, 0);
            acc[rt][0] = __builtin_amdgcn_mfma_f32_16x16x32_bf16(ah0, wlo, acc[rt][0], 0, 0, 0);
            acc[rt][1] = __builtin_amdgcn_mfma_f32_16x16x32_bf16(ah1, whi, acc[rt][1], 0, 0, 0);
            acc[rt][1] = __builtin_amdgcn_mfma_f32_16x16x32_bf16(al1, whi, acc[rt][1], 0, 0, 0);
            acc[rt][1] = __builtin_amdgcn_mfma_f32_16x16x32_bf16(ah1, wlo, acc[rt][1], 0, 0, 0);
        }
    }
}

// ---------------- persistent recurrence kernel ----------------
struct RArgs {
    const float *m1W, *m1b, *Wih1, *Whh1, *bih1, *bhh1;
    const float *m2W, *m2b, *Wih2, *Whh2, *bih2, *bhh2;
    float* XTF;
    u16 *XTH, *XTL;
    float* stF;
    u16* stH;
    float* hs;
    u32* bar;
};

__global__ __launch_bounds__(256, 1) void reck(RArgs A) {
    __shared__ float buf0[16384];     // 64KB
    __shared__ float buf1[16384];     // 64KB
    __shared__ float red[4][32][16];  // 8KB

    const int tid = threadIdx.x, lane = tid & 63, wv = tid >> 6;
    const int blk = blockIdx.x;
    const int layer = blk >> 7;
    const int g = blk & 127;
    const bool isMog = g < 64;
    const int jb = (g & 63) * 16;

    const float* mW  = layer ? A.m2W : A.m1W;
    const float* mb_ = layer ? A.m2b : A.m1b;
    const float* Wih = layer ? A.Wih2 : A.Wih1;
    const float* Whh = layer ? A.Whh2 : A.Whh1;
    const float* bih = layer ? A.bih2 : A.bih1;
    const float* bhh = layer ? A.bhh2 : A.bhh1;

    float* hF  = A.stF + layer * 32768;
    float* hmF = A.stF + 65536 + layer * 32768;
    float* cS  = A.stF + 131072 + layer * 32768;
    float* rFb = A.stF + 196608;
    u16* hH  = A.stH + layer * 32768;
    u16* hmH = A.stH + 65536 + layer * 32768;
    u16* rHb = A.stH + 131072;
    u16* hL  = A.stH + 196608 + layer * 32768;
    u16* hmL = A.stH + 262144 + layer * 32768;
    u16* rLb = A.stH + 327680;

    u32 bcnt = 0;
    int cur = 0;
    const int col = lane & 15, kq4 = lane >> 4;

    // prologue staging
    if (isMog) stage_mogF(mW, jb, buf0, lane, wv);
    else       stage_lstmF(Whh, jb, 0, buf0, lane, wv);

    for (int s = 0; s <= 64; ++s) {
        const bool act = layer ? (s > 0) : (s < 64);
        const int t = layer ? s - 1 : s;
        const int tt = act ? t : 0;
        const int rb = tt & 1;

        float* xF; u16 *xH, *xL;
        if (layer == 0) {
            xF = A.XTF + (size_t)tt * 32768;
            xH = A.XTH + (size_t)tt * 32768;
            xL = A.XTL + (size_t)tt * 32768;
        } else {
            xF = rFb + rb * 32768;
            xH = rHb + rb * 32768;
            xL = rLb + rb * 32768;
        }

        if (isMog) {
            for (int ph = 0; ph < 5; ++ph) {
                float* wsrc = cur ? buf1 : buf0;
                float* wdst = cur ? buf0 : buf1;
                if (act) {
                    const u16 *gH, *gL; const float* srcF; float* dF; u16 *dH, *dL;
                    switch (ph) {
                        case 0:  gH = hH;  gL = hL;  srcF = xF;  dF = xF;  dH = xH;  dL = xL;  break;
                        case 1:  gH = xH;  gL = xL;  srcF = hF;  dF = hmF; dH = hmH; dL = hmL; break;
                        case 2:  gH = hmH; gL = hmL; srcF = xF;  dF = xF;  dH = xH;  dL = xL;  break;
                        case 3:  gH = xH;  gL = xL;  srcF = hmF; dF = hmF; dH = hmH; dL = hmL; break;
                        default: gH = hmH; gL = hmL; srcF = xF;  dF = xF;  dH = xH;  dL = xL;  break;
                    }
                    asm volatile("s_waitcnt vmcnt(0)" ::: "memory");  // my self-staged weights ready
                    f32x4 a0 = {0.f, 0.f, 0.f, 0.f}, a1 = {0.f, 0.f, 0.f, 0.f};
#pragma unroll
                    for (int kt = 0; kt < 8; ++kt) {
                        int octc = wv * 32 + kt * 4 + kq4;
                        const float* wp = wsrc + octc * 128 + col * 8;
                        f32x4 w0 = *(const f32x4*)wp, w1 = *(const f32x4*)(wp + 4);
                        bf16x8 whi = mkfrag(pkhi(w0.x, w0.y), pkhi(w0.z, w0.w),
                                            pkhi(w1.x, w1.y), pkhi(w1.z, w1.w));
                        bf16x8 wlo = mkfrag(pklo(w0.x, w0.y), pklo(w0.z, w0.w),
                                            pklo(w1.x, w1.y), pklo(w1.z, w1.w));
                        const u16* pH = gH + ((size_t)octc * 32 + col) * 8;
                        const u16* pL = gL + ((size_t)octc * 32 + col) * 8;
                        bf16x8 ah0 = ldA(pH), ah1 = ldA(pH + 128);
                        bf16x8 al0 = ldA(pL), al1 = ldA(pL + 128);
                        a0 = __builtin_amdgcn_mfma_f32_16x16x32_bf16(ah0, whi, a0, 0, 0, 0);
                        a0 = __builtin_amdgcn_mfma_f32_16x16x32_bf16(al0, whi, a0, 0, 0, 0);
                        a0 = __builtin_amdgcn_mfma_f32_16x16x32_bf16(ah0, wlo, a0, 0, 0, 0);
                        a1 = __builtin_amdgcn_mfma_f32_16x16x32_bf16(ah1, whi, a1, 0, 0, 0);
                        a1 = __builtin_amdgcn_mfma_f32_16x16x32_bf16(al1, whi, a1, 0, 0, 0);
                        a1 = __builtin_amdgcn_mfma_f32_16x16x32_bf16(ah1, wlo, a1, 0, 0, 0);
                    }
#pragma unroll
                    for (int mh = 0; mh < 2; ++mh) {
                        f32x4 av = mh ? a1 : a0;
#pragma unroll
                        for (int r = 0; r < 4; ++r)
                            red[wv][mh * 16 + kq4 * 4 + r][col] = av[r];
                    }
                    __syncthreads();
#pragma unroll
                    for (int uu = 0; uu < 2; ++uu) {
                        int u = tid + uu * 256;
                        int jj = u & 15, bb = u >> 4;
                        float sv = red[0][bb][jj] + red[1][bb][jj]
                                 + red[2][bb][jj] + red[3][bb][jj];
                        int d = jb + jj;
                        sv += mb_[ph * 1024 + d];
                        float gate = 2.0f * sigmoidf_(sv);
                        size_t pidx = ((size_t)(d >> 3) * 32 + bb) * 8 + (d & 7);
                        float val = gate * ldc4(srcF + pidx);
                        stc4(dF + pidx, val);
                        u32 uv = __float_as_uint(val);
                        stc2(dH + pidx, (u16)(uv >> 16));
                        float lov = val - __uint_as_float(uv & 0xffff0000u);
                        stc2(dL + pidx, (u16)(__float_as_uint(lov) >> 16));
                    }
                }
                gbar_arrive(A.bar);
                ++bcnt;
                stage_mogF(mW + (size_t)((ph + 1) % 5) * 1048576, jb, wdst, lane, wv);
                gbar_wait(A.bar, bcnt);
                cur ^= 1;
            }
            // lstm-tail barrier
            gbar_arrive(A.bar);
            ++bcnt;
            gbar_wait(A.bar, bcnt);
        } else {
            // ph0..ph3: arrive+wait only (weights prestaged at previous tail)
#pragma unroll
            for (int ph = 0; ph < 4; ++ph) {
                gbar_arrive(A.bar);
                ++bcnt;
                gbar_wait(A.bar, bcnt);
            }
            f32x4 acc[4][2];
#pragma unroll
            for (int rt = 0; rt < 4; ++rt) {
                acc[rt][0] = (f32x4){0.f, 0.f, 0.f, 0.f};
                acc[rt][1] = (f32x4){0.f, 0.f, 0.f, 0.f};
            }
            // ---- Whh side (hm final after ph3), overlapping mog ph4 ----
            if (act) {
#pragma unroll
                for (int c = 0; c < 4; ++c) {
                    bf16x8 fr[8];
                    lstm_acts(hmH, hmL, c * 256, lane, wv, fr);
                    asm volatile("s_waitcnt vmcnt(16)" ::: "memory");  // drain stage(c), keep acts
                    if (c < 3) stage_lstmF(Whh, jb, (c + 1) * 256,
                                           ((c + 1) & 1) ? buf1 : buf0, lane, wv);
                    else       stage_lstmF(Wih, jb, 0, buf0, lane, wv);  // c4 = Wih k0
                    lstm_mfma((c & 1) ? buf1 : buf0, fr, lane, wv, acc);
                }
            }
            gbar_arrive(A.bar);   // g5 (after mog ph4) — also drains Wih c0 stage
            ++bcnt;
            gbar_wait(A.bar, bcnt);
            // ---- Wih side (x final after ph4) + gates ----
            if (act) {
#pragma unroll
                for (int c = 0; c < 4; ++c) {
                    bf16x8 fr[8];
                    lstm_acts(xH, xL, c * 256, lane, wv, fr);
                    asm volatile("s_waitcnt vmcnt(16)" ::: "memory");
                    if (c < 3) stage_lstmF(Wih, jb, (c + 1) * 256,
                                           ((c + 1) & 1) ? buf1 : buf0, lane, wv);
                    lstm_mfma((c & 1) ? buf1 : buf0, fr, lane, wv, acc);
                }
                // cross-wave K reduction, one gate at a time
                float gv[2][4];
#pragma unroll
                for (int gt = 0; gt < 4; ++gt) {
                    __syncthreads();
#pragma unroll
                    for (int mh = 0; mh < 2; ++mh) {
                        f32x4 av = acc[gt][mh];
#pragma unroll
                        for (int r = 0; r < 4; ++r)
                            red[wv][mh * 16 + kq4 * 4 + r][col] = av[r];
                    }
                    __syncthreads();
#pragma unroll
                    for (int uu = 0; uu < 2; ++uu) {
                        int u = tid + uu * 256;
                        gv[uu][gt] = red[0][u >> 4][u & 15] + red[1][u >> 4][u & 15]
                                   + red[2][u >> 4][u & 15] + red[3][u >> 4][u & 15];
                    }
                }
#pragma unroll
                for (int uu = 0; uu < 2; ++uu) {
                    int u = tid + uu * 256;
                    int cell = u & 15, bb = u >> 4;
                    int d = jb + cell;
                    float gi = gv[uu][0] + bih[d] + bhh[d];
                    float gf = gv[uu][1] + bih[1024 + d] + bhh[1024 + d];
                    float gg = gv[uu][2] + bih[2048 + d] + bhh[2048 + d];
                    float go = gv[uu][3] + bih[3072 + d] + bhh[3072 + d];
                    int cidx = d * 32 + bb;
                    float cn = sigmoidf_(gf) * cS[cidx] + sigmoidf_(gi) * tanhf_(gg);
                    cS[cidx] = cn;
                    float hn = sigmoidf_(go) * tanhf_(cn);
                    size_t pidx = ((size_t)(d >> 3) * 32 + bb) * 8 + (d & 7);
                    u32 uv = __float_as_uint(hn);
                    u16 hhi = (u16)(uv >> 16);
                    float lov = hn - __uint_as_float(uv & 0xffff0000u);
                    u16 hlo = (u16)(__float_as_uint(lov) >> 16);
                    stc4(hF + pidx, hn);
                    stc2(hH + pidx, hhi);
                    stc2(hL + pidx, hlo);
                    if (layer == 0) {
                        int wb = s & 1;
                        stc4(rFb + wb * 32768 + pidx, hn);
                        stc2(rHb + wb * 32768 + pidx, hhi);
                        stc2(rLb + wb * 32768 + pidx, hlo);
                    } else {
                        A.hs[(size_t)bb * 65536 + (size_t)t * 1024 + d] = hn;
                    }
                }
            }
            gbar_arrive(A.bar);   // g6 (slot end)
            ++bcnt;
            stage_lstmF(Whh, jb, 0, buf0, lane, wv);   // next slot's Whh c0
            gbar_wait(A.bar, bcnt);
        }
    }
}

// ---------------- embedding gather into fp32 + hi/lo bf16 planes ----------------
__global__ __launch_bounds__(256) void gather_embed(const int* __restrict__ seq,
                                                    const float* __restrict__ emb,
                                                    float* __restrict__ XTF,
                                                    u16* __restrict__ XTH,
                                                    u16* __restrict__ XTL) {
    int t = blockIdx.x;
#pragma unroll 4
    for (int i = 0; i < 16; ++i) {
        int u = i * 256 + threadIdx.x;
        int oct = u >> 5, b = u & 31;
        int row = seq[b * 64 + t];
        const float* sp = emb + (size_t)row * 1024 + oct * 8;
        float4 f0 = *(const float4*)sp;
        float4 f1 = *(const float4*)(sp + 4);
        size_t base = (size_t)t * 32768 + ((size_t)oct * 32 + b) * 8;
        *(float4*)(XTF + base) = f0;
        *(float4*)(XTF + base + 4) = f1;
        u32x4 hi = {pkhi(f0.x, f0.y), pkhi(f0.z, f0.w), pkhi(f1.x, f1.y), pkhi(f1.z, f1.w)};
        u32x4 lo = {pklo(f0.x, f0.y), pklo(f0.z, f0.w), pklo(f1.x, f1.y), pklo(f1.z, f1.w)};
        *(u32x4*)(XTH + base) = hi;
        *(u32x4*)(XTL + base) = lo;
    }
}

// ---------------- fp32 -> bf16 (RNE, projection A) ----------------
__global__ __launch_bounds__(256) void f32_to_bf16(const float* __restrict__ in,
                                                   unsigned short* __restrict__ out, int n) {
    int i = (blockIdx.x * 256 + threadIdx.x) * 8;
    if (i + 7 < n) {
        float4 f0 = *(const float4*)(in + i);
        float4 f1 = *(const float4*)(in + i + 4);
        bf16x8 v;
        v[0] = (short)f2bf(f0.x); v[1] = (short)f2bf(f0.y);
        v[2] = (short)f2bf(f0.z); v[3] = (short)f2bf(f0.w);
        v[4] = (short)f2bf(f1.x); v[5] = (short)f2bf(f1.y);
        v[6] = (short)f2bf(f1.z); v[7] = (short)f2bf(f1.w);
        *(bf16x8*)(out + i) = v;
    }
}

// ---------------- output projection (bf16 MFMA, 128x128 tile) ----------------
__global__ __launch_bounds__(256) void out_proj(const unsigned short* __restrict__ hsb,
                                                const float* __restrict__ emb,
                                                const float* __restrict__ fcb,
                                                float* __restrict__ out) {
    __shared__ unsigned short Al[128 * 40];
    __shared__ unsigned short Bl[128 * 40];
    int tid = threadIdx.x;
    int n0 = blockIdx.x * 128;
    int m0 = blockIdx.y * 128;
    int wid = tid >> 6, l = tid & 63;
    int wm = wid >> 1, wn = wid & 1;
    int c16 = l & 15, kg = l >> 4;

    f32x4 acc[4][4];
#pragma unroll
    for (int i = 0; i < 4; i++)
#pragma unroll
        for (int j = 0; j < 4; j++) acc[i][j] = (f32x4){0.f, 0.f, 0.f, 0.f};

    for (int k0 = 0; k0 < 1024; k0 += 32) {
#pragma unroll
        for (int i = 0; i < 2; i++) {
            int id = i * 256 + tid;
            int r = id >> 2, ccc = id & 3;
            *(bf16x8*)&Al[r * 40 + ccc * 8] =
                *(const bf16x8*)(hsb + (size_t)(m0 + r) * 1024 + k0 + ccc * 8);
        }
#pragma unroll
        for (int i = 0; i < 2; i++) {
            int id = i * 256 + tid;
            int r = id >> 2, ccc = id & 3;
            const float* src = emb + (size_t)(n0 + r) * 1024 + k0 + ccc * 8;
            float4 f0 = *(const float4*)(src);
            float4 f1 = *(const float4*)(src + 4);
            bf16x8 v;
            v[0] = (short)f2bf(f0.x); v[1] = (short)f2bf(f0.y);
            v[2] = (short)f2bf(f0.z); v[3] = (short)f2bf(f0.w);
            v[4] = (short)f2bf(f1.x); v[5] = (short)f2bf(f1.y);
            v[6] = (short)f2bf(f1.z); v[7] = (short)f2bf(f1.w);
            *(bf16x8*)&Bl[r * 40 + ccc * 8] = v;
        }
        __syncthreads();

        bf16x8 afr[4], bfr[4];
#pragma unroll
        for (int i = 0; i < 4; i++)
            afr[i] = *(const bf16x8*)&Al[(wm * 64 + i * 16 + c16) * 40 + kg * 8];
#pragma unroll
        for (int j = 0; j < 4; j++)
            bfr[j] = *(const bf16x8*)&Bl[(wn * 64 + j * 16 + c16) * 40 + kg * 8];
#pragma unroll
        for (int i = 0; i < 4; i++)
#pragma unroll
            for (int j = 0; j < 4; j++)
                acc[i][j] = __builtin_amdgcn_mfma_f32_16x16x32_bf16(afr[i], bfr[j], acc[i][j], 0, 0, 0);
        __syncthreads();
    }

#pragma unroll
    for (int i = 0; i < 4; i++) {
        int row = m0 + wm * 64 + i * 16 + kg * 4;
#pragma unroll
        for (int j = 0; j < 4; j++) {
            int col = n0 + wn * 64 + j * 16 + c16;
            float fb = fcb[col];
#pragma unroll
            for (int r = 0; r < 4; r++)
                out[(size_t)(row + r) * 32000 + col] = acc[i][j][r] + fb;
        }
    }
}

// ---------------- host ----------------
extern "C" void kernel_launch(void* const* d_in, const int* in_sizes, int n_in,
                              void* d_out, int out_size, void* d_ws, size_t ws_size,
                              hipStream_t stream) {
    const int*   seq    = (const int*)d_in[0];
    const float* emb    = (const float*)d_in[2];
    const float* mog1_W = (const float*)d_in[3];
    const float* mog1_b = (const float*)d_in[4];
    const float* W_ih1  = (const float*)d_in[5];
    const float* W_hh1  = (const float*)d_in[6];
    const float* b_ih1  = (const float*)d_in[7];
    const float* b_hh1  = (const float*)d_in[8];
    const float* mog2_W = (const float*)d_in[9];
    const float* mog2_b = (const float*)d_in[10];
    const float* W_ih2  = (const float*)d_in[11];
    const float* W_hh2  = (const float*)d_in[12];
    const float* b_ih2  = (const float*)d_in[13];
    const float* b_hh2  = (const float*)d_in[14];
    const float* fc_b   = (const float*)d_in[15];

    char* ws = (char*)d_ws;
    float* XTF = (float*)ws;                                  // 8 MB
    u16*   XTH = (u16*)(ws + 8388608);                        // 4 MB
    u16*   XTL = (u16*)(ws + 12582912);                       // 4 MB
    float* stF = (float*)(ws + 16777216);                     // 1 MB
    u16*   stH = (u16*)(ws + 17825792);                       // 768 KB
    u32*   bar = (u32*)(ws + 18874368);                       // 16 KB
    unsigned short* hsb = (unsigned short*)(ws + 18890752);   // 4 MB

    float* out0 = (float*)d_out;
    float* hs   = out0 + 65536000LL;

    hipMemsetAsync(stF, 0, 1835008, stream);
    hipMemsetAsync(bar, 0, 16384, stream);

    gather_embed<<<64, 256, 0, stream>>>(seq, emb, XTF, XTH, XTL);

    RArgs a;
    a.m1W = mog1_W; a.m1b = mog1_b;
    a.Wih1 = W_ih1; a.Whh1 = W_hh1; a.bih1 = b_ih1; a.bhh1 = b_hh1;
    a.m2W = mog2_W; a.m2b = mog2_b;
    a.Wih2 = W_ih2; a.Whh2 = W_hh2; a.bih2 = b_ih2; a.bhh2 = b_hh2;
    a.XTF = XTF; a.XTH = XTH; a.XTL = XTL;
    a.stF = stF; a.stH = stH; a.hs = hs; a.bar = bar;

    reck<<<256, 256, 0, stream>>>(a);

    f32_to_bf16<<<1024, 256, 0, stream>>>(hs, hsb, 2097152);
    out_proj<<<dim3(250, 16), 256, 0, stream>>>(hsb, emb, fc_b, out0);
}

// Round 9
// 3967.631 us; speedup vs baseline: 1.7163x; 1.2150x over previous
//
#include <hip/hip_runtime.h>

typedef short bf16x8 __attribute__((ext_vector_type(8)));
typedef float f32x4 __attribute__((ext_vector_type(4)));
typedef unsigned int u32;
typedef u32 u32x4 __attribute__((ext_vector_type(4)));
typedef unsigned short u16;
typedef unsigned long long u64;

static __device__ __forceinline__ unsigned short f2bf(float f) {
    unsigned int u = __float_as_uint(f);
    unsigned int r = (u + 0x7fffu + ((u >> 16) & 1u)) >> 16;
    return (unsigned short)r;
}
static __device__ __forceinline__ float sigmoidf_(float x) {
    return 1.0f / (1.0f + __expf(-x));
}
static __device__ __forceinline__ float tanhf_(float x) {
    return 2.0f / (1.0f + __expf(-2.0f * x)) - 1.0f;
}

// truncation-split packing: fp32 -> (hi bf16, lo bf16)
static __device__ __forceinline__ u32 pkhi(float a, float b) {
    return (__float_as_uint(a) >> 16) | (__float_as_uint(b) & 0xffff0000u);
}
static __device__ __forceinline__ u32 pklo(float a, float b) {
    float la = a - __uint_as_float(__float_as_uint(a) & 0xffff0000u);
    float lb = b - __uint_as_float(__float_as_uint(b) & 0xffff0000u);
    return (__float_as_uint(la) >> 16) | (__float_as_uint(lb) & 0xffff0000u);
}
static __device__ __forceinline__ bf16x8 mkfrag(u32 a, u32 b, u32 c, u32 d) {
    u32x4 v = {a, b, c, d};
    return __builtin_bit_cast(bf16x8, v);
}

// ---- sc1 coherent activation access (fence-free scheme) ----
static __device__ __forceinline__ bf16x8 ldA(const u16* p) {
    u64 a = __hip_atomic_load((const u64*)p, __ATOMIC_RELAXED, __HIP_MEMORY_SCOPE_AGENT);
    u64 b = __hip_atomic_load((const u64*)(p + 4), __ATOMIC_RELAXED, __HIP_MEMORY_SCOPE_AGENT);
    union { u64 q[2]; bf16x8 v; } u;
    u.q[0] = a; u.q[1] = b;
    return u.v;
}
static __device__ __forceinline__ float ldc4(const float* p) {
    return __hip_atomic_load(p, __ATOMIC_RELAXED, __HIP_MEMORY_SCOPE_AGENT);
}
static __device__ __forceinline__ void stc4(float* p, float v) {
    __hip_atomic_store(p, v, __ATOMIC_RELAXED, __HIP_MEMORY_SCOPE_AGENT);
}
static __device__ __forceinline__ void stc2(u16* p, u16 v) {
    __hip_atomic_store(p, v, __ATOMIC_RELAXED, __HIP_MEMORY_SCOPE_AGENT);
}

static __device__ __forceinline__ void dma16(const float* g, float* l) {
    __builtin_amdgcn_global_load_lds((const __attribute__((address_space(1))) void*)g,
                                     (__attribute__((address_space(3))) void*)l, 16, 0, 0);
}

// ---------------- barriers ----------------
// bar layout (u32): arrival line i at bar[i*32], i=0..63 (layer0: 0-31, layer1: 32-63);
// gen[layer] at bar[2112 + layer*32]. Masters: block 0 (layer0), block 128 (layer1).
static __device__ __forceinline__ void arrA(u32* bar, int line) {   // active: publish stores
    asm volatile("s_waitcnt vmcnt(0) lgkmcnt(0)" ::: "memory");
    __builtin_amdgcn_s_barrier();
    if (threadIdx.x == 0)
        __hip_atomic_fetch_add(bar + line * 32, 1u, __ATOMIC_RELAXED, __HIP_MEMORY_SCOPE_AGENT);
}
static __device__ __forceinline__ void arrP(u32* bar, int line) {   // passive: stages keep flying
    __builtin_amdgcn_s_barrier();
    if (threadIdx.x == 0)
        __hip_atomic_fetch_add(bar + line * 32, 1u, __ATOMIC_RELAXED, __HIP_MEMORY_SCOPE_AGENT);
}
static __device__ __forceinline__ void bwait(u32* bar, int layer, bool master,
                                             bool glob, u32 target) {
    if (master) {
        if (threadIdx.x < 64) {
            const u32 tgt = glob ? (target << 8) : (target << 7);   // 256 or 128 arrivals
            int line = glob ? (int)threadIdx.x : layer * 32 + (int)(threadIdx.x & 31);
            bool on = glob || (threadIdx.x < 32);
            for (;;) {
                u32 v = on ? __hip_atomic_load(bar + line * 32, __ATOMIC_RELAXED,
                                               __HIP_MEMORY_SCOPE_AGENT) : 0u;
                v += __shfl_xor(v, 1);
                v += __shfl_xor(v, 2);
                v += __shfl_xor(v, 4);
                v += __shfl_xor(v, 8);
                v += __shfl_xor(v, 16);
                v += __shfl_xor(v, 32);
                if (v >= tgt) break;
                __builtin_amdgcn_s_sleep(1);
            }
            if (threadIdx.x == 0)
                __hip_atomic_store(bar + 2112 + layer * 32, target, __ATOMIC_RELAXED,
                                   __HIP_MEMORY_SCOPE_AGENT);
        }
    } else {
        if (threadIdx.x == 0) {
            while (__hip_atomic_load(bar + 2112 + layer * 32, __ATOMIC_RELAXED,
                                     __HIP_MEMORY_SCOPE_AGENT) < target)
                __builtin_amdgcn_s_sleep(1);
        }
    }
    __builtin_amdgcn_s_barrier();
    asm volatile("" ::: "memory");
}

// ---------------- weight staging (self-staged: wave stages exactly what it reads) -----
// mog: 16 rows x 1024 k fp32 = 64KB; LDS float idx = oct*128 + row*8 + half*4.
static __device__ __forceinline__ void stage_mogF(const float* W, int jb, float* lbuf,
                                                  int lane, int wv) {
    int oct2 = lane >> 5, row = (lane >> 1) & 15, half = lane & 1;
#pragma unroll
    for (int i = 0; i < 16; ++i) {
        int og = wv * 16 + i;
        const float* src = W + (size_t)(jb + row) * 1024 + (og * 2 + oct2) * 8 + half * 4;
        dma16(src, lbuf + og * 256);
    }
}
// lstm chunk: 64 rows (4 gates x 16 cells) x 128 k = 32KB; idx = octl*512 + rowc*8 + half*4.
static __device__ __forceinline__ void stage_l128(const float* Ws, int jb, int kb,
                                                  float* lbuf, int lane, int wv) {
    int half = lane & 1;
#pragma unroll
    for (int i = 0; i < 8; ++i) {
        int octl = wv * 4 + (i >> 1);
        int rh = i & 1;
        int rowc = rh * 32 + (lane >> 1);
        int grow = (rowc >> 4) * 1024 + jb + (rowc & 15);
        const float* src = Ws + (size_t)grow * 1024 + kb + octl * 8 + half * 4;
        dma16(src, lbuf + octl * 512 + rh * 256);
    }
}

// ---------------- lstm chunk pieces ----------------
static __device__ __forceinline__ void l_acts(const u16* aH, const u16* aL, int cidx,
                                              int lane, int wv, bf16x8 fr[4]) {
    const int col = lane & 15, kq4 = lane >> 4;
    size_t octa = (size_t)cidx * 16 + wv * 4 + kq4;
    const u16* pH = aH + (octa * 32 + col) * 8;
    const u16* pL = aL + (octa * 32 + col) * 8;
    fr[0] = ldA(pH);
    fr[1] = ldA(pH + 128);
    fr[2] = ldA(pL);
    fr[3] = ldA(pL + 128);
}
static __device__ __forceinline__ void l_mfma(const float* lbuf, const bf16x8 fr[4],
                                              int lane, int wv, f32x4 (&acc)[4][2]) {
    const int col = lane & 15, kq4 = lane >> 4;
    const float* wbase = lbuf + (wv * 4 + kq4) * 512;
#pragma unroll
    for (int rt = 0; rt < 4; ++rt) {
        const float* wp = wbase + (rt * 16 + col) * 8;
        f32x4 w0 = *(const f32x4*)wp, w1 = *(const f32x4*)(wp + 4);
        bf16x8 whi = mkfrag(pkhi(w0.x, w0.y), pkhi(w0.z, w0.w),
                            pkhi(w1.x, w1.y), pkhi(w1.z, w1.w));
        bf16x8 wlo = mkfrag(pklo(w0.x, w0.y), pklo(w0.z, w0.w),
                            pklo(w1.x, w1.y), pklo(w1.z, w1.w));
        acc[rt][0] = __builtin_amdgcn_mfma_f32_16x16x32_bf16(fr[0], whi, acc[rt][0], 0, 0, 0);
        acc[rt][0] = __builtin_amdgcn_mfma_f32_16x16x32_bf16(fr[2], whi, acc[rt][0], 0, 0, 0);
        acc[rt][0] = __builtin_amdgcn_mfma_f32_16x16x32_bf16(fr[0], wlo, acc[rt][0], 0, 0, 0);
        acc[rt][1] = __builtin_amdgcn_mfma_f32_16x16x32_bf16(fr[1], whi, acc[rt][1], 0, 0, 0);
        acc[rt][1] = __builtin_amdgcn_mfma_f32_16x16x32_bf16(fr[3], whi, acc[rt][1], 0, 0, 0);
        acc[rt][1] = __builtin_amdgcn_mfma_f32_16x16x32_bf16(fr[1], wlo, acc[rt][1], 0, 0, 0);
    }
}

// ---------------- persistent recurrence kernel ----------------
struct RArgs {
    const float *m1W, *m1b, *Wih1, *Whh1, *bih1, *bhh1;
    const float *m2W, *m2b, *Wih2, *Whh2, *bih2, *bhh2;
    float* XTF;
    u16 *XTH, *XTL;
    float* stF;
    u16* stH;
    float* hs;
    u32* bar;
};

__global__ __launch_bounds__(256, 1) void reck(RArgs A) {
    __shared__ float wbuf[4][8192];   // 4 x 32KB (mog: 2 x 64KB)
    __shared__ float red[4][32][16];  // 8KB

    const int tid = threadIdx.x, lane = tid & 63, wv = tid >> 6;
    const int col = lane & 15, kq4 = lane >> 4;
    const int blk = blockIdx.x;
    const int layer = blk >> 7;
    const int g = blk & 127;
    const bool isMog = g < 64;
    const bool master = (g == 0);
    const int line = layer * 32 + (g & 31);
    const int jb = (g & 63) * 16;

    const float* mW  = layer ? A.m2W : A.m1W;
    const float* mb_ = layer ? A.m2b : A.m1b;
    const float* Wih = layer ? A.Wih2 : A.Wih1;
    const float* Whh = layer ? A.Whh2 : A.Whh1;
    const float* bih = layer ? A.bih2 : A.bih1;
    const float* bhh = layer ? A.bhh2 : A.bhh1;

    float* hF  = A.stF + layer * 32768;
    float* hmF = A.stF + 65536 + layer * 32768;
    float* cS  = A.stF + 131072 + layer * 32768;
    float* rFb = A.stF + 196608;
    u16* hH  = A.stH + layer * 32768;
    u16* hmH = A.stH + 65536 + layer * 32768;
    u16* rHb = A.stH + 131072;
    u16* hL  = A.stH + 196608 + layer * 32768;
    u16* hmL = A.stH + 262144 + layer * 32768;
    u16* rLb = A.stH + 327680;

    float* mbuf0 = &wbuf[0][0];
    float* mbuf1 = &wbuf[2][0];

    u32 bcnt = 0;
    int cur = 0;

    if (isMog) stage_mogF(mW, jb, mbuf0, lane, wv);   // prologue: ph0 weights

    for (int s = 0; s <= 64; ++s) {
        const bool act = layer ? (s > 0) : (s < 64);
        const int t = layer ? s - 1 : s;
        const int tt = act ? t : 0;
        const int rb = tt & 1;

        float* xF; u16 *xH, *xL;
        if (layer == 0) {
            xF = A.XTF + (size_t)tt * 32768;
            xH = A.XTH + (size_t)tt * 32768;
            xL = A.XTL + (size_t)tt * 32768;
        } else {
            xF = rFb + rb * 32768;
            xH = rHb + rb * 32768;
            xL = rLb + rb * 32768;
        }

        if (isMog) {
            for (int ph = 0; ph < 5; ++ph) {
                float* wsrc = cur ? mbuf1 : mbuf0;
                float* wdst = cur ? mbuf0 : mbuf1;
                if (act) {
                    const u16 *gH, *gL; const float* srcF; float* dF; u16 *dH, *dL;
                    switch (ph) {
                        case 0:  gH = hH;  gL = hL;  srcF = xF;  dF = xF;  dH = xH;  dL = xL;  break;
                        case 1:  gH = xH;  gL = xL;  srcF = hF;  dF = hmF; dH = hmH; dL = hmL; break;
                        case 2:  gH = hmH; gL = hmL; srcF = xF;  dF = xF;  dH = xH;  dL = xL;  break;
                        case 3:  gH = xH;  gL = xL;  srcF = hmF; dF = hmF; dH = hmH; dL = hmL; break;
                        default: gH = hmH; gL = hmL; srcF = xF;  dF = xF;  dH = xH;  dL = xL;  break;
                    }
                    // (1) act fragments up front — acts precede the stage in the vmcnt queue
                    bf16x8 AH0[8], AH1[8], AL0[8], AL1[8];
#pragma unroll
                    for (int kt = 0; kt < 8; ++kt) {
                        int octc = wv * 32 + kt * 4 + kq4;
                        const u16* pH = gH + ((size_t)octc * 32 + col) * 8;
                        const u16* pL = gL + ((size_t)octc * 32 + col) * 8;
                        AH0[kt] = ldA(pH);  AH1[kt] = ldA(pH + 128);
                        AL0[kt] = ldA(pL);  AL1[kt] = ldA(pL + 128);
                    }
                    // (2) next-phase stage: flies during compute + barrier
                    stage_mogF(mW + (size_t)((ph + 1) % 5) * 1048576, jb, wdst, lane, wv);
                    // (3) MFMA
                    f32x4 a0 = {0.f, 0.f, 0.f, 0.f}, a1 = {0.f, 0.f, 0.f, 0.f};
#pragma unroll
                    for (int kt = 0; kt < 8; ++kt) {
                        int octc = wv * 32 + kt * 4 + kq4;
                        const float* wp = wsrc + octc * 128 + col * 8;
                        f32x4 w0 = *(const f32x4*)wp, w1 = *(const f32x4*)(wp + 4);
                        bf16x8 whi = mkfrag(pkhi(w0.x, w0.y), pkhi(w0.z, w0.w),
                                            pkhi(w1.x, w1.y), pkhi(w1.z, w1.w));
                        bf16x8 wlo = mkfrag(pklo(w0.x, w0.y), pklo(w0.z, w0.w),
                                            pklo(w1.x, w1.y), pklo(w1.z, w1.w));
                        a0 = __builtin_amdgcn_mfma_f32_16x16x32_bf16(AH0[kt], whi, a0, 0, 0, 0);
                        a0 = __builtin_amdgcn_mfma_f32_16x16x32_bf16(AL0[kt], whi, a0, 0, 0, 0);
                        a0 = __builtin_amdgcn_mfma_f32_16x16x32_bf16(AH0[kt], wlo, a0, 0, 0, 0);
                        a1 = __builtin_amdgcn_mfma_f32_16x16x32_bf16(AH1[kt], whi, a1, 0, 0, 0);
                        a1 = __builtin_amdgcn_mfma_f32_16x16x32_bf16(AL1[kt], whi, a1, 0, 0, 0);
                        a1 = __builtin_amdgcn_mfma_f32_16x16x32_bf16(AH1[kt], wlo, a1, 0, 0, 0);
                    }
                    // (4) cross-wave reduce + gate + publish
#pragma unroll
                    for (int mh = 0; mh < 2; ++mh) {
                        f32x4 av = mh ? a1 : a0;
#pragma unroll
                        for (int r = 0; r < 4; ++r)
                            red[wv][mh * 16 + kq4 * 4 + r][col] = av[r];
                    }
                    __syncthreads();
#pragma unroll
                    for (int uu = 0; uu < 2; ++uu) {
                        int u = tid + uu * 256;
                        int jj = u & 15, bb = u >> 4;
                        float sv = red[0][bb][jj] + red[1][bb][jj]
                                 + red[2][bb][jj] + red[3][bb][jj];
                        int d = jb + jj;
                        sv += mb_[ph * 1024 + d];
                        float gate = 2.0f * sigmoidf_(sv);
                        size_t pidx = ((size_t)(d >> 3) * 32 + bb) * 8 + (d & 7);
                        float val = gate * ldc4(srcF + pidx);
                        stc4(dF + pidx, val);
                        u32 uv = __float_as_uint(val);
                        stc2(dH + pidx, (u16)(uv >> 16));
                        float lov = val - __uint_as_float(uv & 0xffff0000u);
                        stc2(dL + pidx, (u16)(__float_as_uint(lov) >> 16));
                    }
                } else {
                    stage_mogF(mW + (size_t)((ph + 1) % 5) * 1048576, jb, wdst, lane, wv);
                }
                arrA(A.bar, line);                    // publish + drain own stage
                ++bcnt;
                bwait(A.bar, layer, master, false, bcnt);
                cur ^= 1;
            }
            // g6 (global slot barrier): mog idle since g5, passive
            arrP(A.bar, line);
            ++bcnt;
            bwait(A.bar, layer, master, true, bcnt);
        } else {
            // ---------- LSTM block ----------
            if (act) {
#pragma unroll
                for (int c = 0; c < 4; ++c)           // Whh c0..c3 fly through ph0-ph3
                    stage_l128(Whh, jb, c * 128, &wbuf[c][0], lane, wv);
            }
#pragma unroll
            for (int p = 0; p < 4; ++p) {             // b1..b4 (ends of ph0..ph3)
                arrP(A.bar, line);
                ++bcnt;
                bwait(A.bar, layer, false, false, bcnt);
            }
            // arrive at g5 BEFORE Whh compute: g5 gated only by mog ph4
            arrP(A.bar, line);
            ++bcnt;
            u32 g5t = bcnt;
            f32x4 acc[4][2];
#pragma unroll
            for (int rt = 0; rt < 4; ++rt) {
                acc[rt][0] = (f32x4){0.f, 0.f, 0.f, 0.f};
                acc[rt][1] = (f32x4){0.f, 0.f, 0.f, 0.f};
            }
            if (act) {
                for (int c = 0; c < 8; ++c) {         // Whh side (overlaps mog ph4)
                    bf16x8 fr[4];
                    l_acts(hmH, hmL, c, lane, wv, fr);
                    l_mfma(&wbuf[c & 3][0], fr, lane, wv, acc);
                    int cn = c + 4;
                    if (cn < 8) stage_l128(Whh, jb, cn * 128, &wbuf[cn & 3][0], lane, wv);
                    else        stage_l128(Wih, jb, (cn - 8) * 128, &wbuf[cn & 3][0], lane, wv);
                }
            }
            bwait(A.bar, layer, false, false, g5t);   // x ready
            if (act) {
                for (int c = 8; c < 16; ++c) {        // Wih side
                    bf16x8 fr[4];
                    l_acts(xH, xL, c - 8, lane, wv, fr);
                    l_mfma(&wbuf[c & 3][0], fr, lane, wv, acc);
                    int cn = c + 4;
                    if (cn < 16) stage_l128(Wih, jb, (cn - 8) * 128, &wbuf[cn & 3][0], lane, wv);
                }
                // cross-wave K reduction, gates, state update
                float gv[2][4];
#pragma unroll
                for (int gt = 0; gt < 4; ++gt) {
                    __syncthreads();
#pragma unroll
                    for (int mh = 0; mh < 2; ++mh) {
                        f32x4 av = acc[gt][mh];
#pragma unroll
                        for (int r = 0; r < 4; ++r)
                            red[wv][mh * 16 + kq4 * 4 + r][col] = av[r];
                    }
                    __syncthreads();
#pragma unroll
                    for (int uu = 0; uu < 2; ++uu) {
                        int u = tid + uu * 256;
                        gv[uu][gt] = red[0][u >> 4][u & 15] + red[1][u >> 4][u & 15]
                                   + red[2][u >> 4][u & 15] + red[3][u >> 4][u & 15];
                    }
                }
#pragma unroll
                for (int uu = 0; uu < 2; ++uu) {
                    int u = tid + uu * 256;
                    int cell = u & 15, bb = u >> 4;
                    int d = jb + cell;
                    float gi = gv[uu][0] + bih[d] + bhh[d];
                    float gf = gv[uu][1] + bih[1024 + d] + bhh[1024 + d];
                    float gg = gv[uu][2] + bih[2048 + d] + bhh[2048 + d];
                    float go = gv[uu][3] + bih[3072 + d] + bhh[3072 + d];
                    int cidx = d * 32 + bb;
                    float cn = sigmoidf_(gf) * cS[cidx] + sigmoidf_(gi) * tanhf_(gg);
                    cS[cidx] = cn;
                    float hn = sigmoidf_(go) * tanhf_(cn);
                    size_t pidx = ((size_t)(d >> 3) * 32 + bb) * 8 + (d & 7);
                    u32 uv = __float_as_uint(hn);
                    u16 hhi = (u16)(uv >> 16);
                    float lov = hn - __uint_as_float(uv & 0xffff0000u);
                    u16 hlo = (u16)(__float_as_uint(lov) >> 16);
                    stc4(hF + pidx, hn);
                    stc2(hH + pidx, hhi);
                    stc2(hL + pidx, hlo);
                    if (layer == 0) {
                        int wb = s & 1;
                        stc4(rFb + wb * 32768 + pidx, hn);
                        stc2(rHb + wb * 32768 + pidx, hhi);
                        stc2(rLb + wb * 32768 + pidx, hlo);
                    } else {
                        A.hs[(size_t)bb * 65536 + (size_t)t * 1024 + d] = hn;
                    }
                }
                arrA(A.bar, line);                    // g6: publish h
            } else {
                arrP(A.bar, line);
            }
            ++bcnt;
            bwait(A.bar, layer, false, true, bcnt);   // global slot barrier
        }
    }
}

// ---------------- embedding gather into fp32 + hi/lo bf16 planes ----------------
__global__ __launch_bounds__(256) void gather_embed(const int* __restrict__ seq,
                                                    const float* __restrict__ emb,
                                                    float* __restrict__ XTF,
                                                    u16* __restrict__ XTH,
                                                    u16* __restrict__ XTL) {
    int t = blockIdx.x;
#pragma unroll 4
    for (int i = 0; i < 16; ++i) {
        int u = i * 256 + threadIdx.x;
        int oct = u >> 5, b = u & 31;
        int row = seq[b * 64 + t];
        const float* sp = emb + (size_t)row * 1024 + oct * 8;
        float4 f0 = *(const float4*)sp;
        float4 f1 = *(const float4*)(sp + 4);
        size_t base = (size_t)t * 32768 + ((size_t)oct * 32 + b) * 8;
        *(float4*)(XTF + base) = f0;
        *(float4*)(XTF + base + 4) = f1;
        u32x4 hi = {pkhi(f0.x, f0.y), pkhi(f0.z, f0.w), pkhi(f1.x, f1.y), pkhi(f1.z, f1.w)};
        u32x4 lo = {pklo(f0.x, f0.y), pklo(f0.z, f0.w), pklo(f1.x, f1.y), pklo(f1.z, f1.w)};
        *(u32x4*)(XTH + base) = hi;
        *(u32x4*)(XTL + base) = lo;
    }
}

// ---------------- fp32 -> bf16 (RNE, projection A) ----------------
__global__ __launch_bounds__(256) void f32_to_bf16(const float* __restrict__ in,
                                                   unsigned short* __restrict__ out, int n) {
    int i = (blockIdx.x * 256 + threadIdx.x) * 8;
    if (i + 7 < n) {
        float4 f0 = *(const float4*)(in + i);
        float4 f1 = *(const float4*)(in + i + 4);
        bf16x8 v;
        v[0] = (short)f2bf(f0.x); v[1] = (short)f2bf(f0.y);
        v[2] = (short)f2bf(f0.z); v[3] = (short)f2bf(f0.w);
        v[4] = (short)f2bf(f1.x); v[5] = (short)f2bf(f1.y);
        v[6] = (short)f2bf(f1.z); v[7] = (short)f2bf(f1.w);
        *(bf16x8*)(out + i) = v;
    }
}

// ---------------- output projection (bf16 MFMA, 128x128 tile) ----------------
__global__ __launch_bounds__(256) void out_proj(const unsigned short* __restrict__ hsb,
                                                const float* __restrict__ emb,
                                                const float* __restrict__ fcb,
                                                float* __restrict__ out) {
    __shared__ unsigned short Al[128 * 40];
    __shared__ unsigned short Bl[128 * 40];
    int tid = threadIdx.x;
    int n0 = blockIdx.x * 128;
    int m0 = blockIdx.y * 128;
    int wid = tid >> 6, l = tid & 63;
    int wm = wid >> 1, wn = wid & 1;
    int c16 = l & 15, kg = l >> 4;

    f32x4 acc[4][4];
#pragma unroll
    for (int i = 0; i < 4; i++)
#pragma unroll
        for (int j = 0; j < 4; j++) acc[i][j] = (f32x4){0.f, 0.f, 0.f, 0.f};

    for (int k0 = 0; k0 < 1024; k0 += 32) {
#pragma unroll
        for (int i = 0; i < 2; i++) {
            int id = i * 256 + tid;
            int r = id >> 2, ccc = id & 3;
            *(bf16x8*)&Al[r * 40 + ccc * 8] =
                *(const bf16x8*)(hsb + (size_t)(m0 + r) * 1024 + k0 + ccc * 8);
        }
#pragma unroll
        for (int i = 0; i < 2; i++) {
            int id = i * 256 + tid;
            int r = id >> 2, ccc = id & 3;
            const float* src = emb + (size_t)(n0 + r) * 1024 + k0 + ccc * 8;
            float4 f0 = *(const float4*)(src);
            float4 f1 = *(const float4*)(src + 4);
            bf16x8 v;
            v[0] = (short)f2bf(f0.x); v[1] = (short)f2bf(f0.y);
            v[2] = (short)f2bf(f0.z); v[3] = (short)f2bf(f0.w);
            v[4] = (short)f2bf(f1.x); v[5] = (short)f2bf(f1.y);
            v[6] = (short)f2bf(f1.z); v[7] = (short)f2bf(f1.w);
            *(bf16x8*)&Bl[r * 40 + ccc * 8] = v;
        }
        __syncthreads();

        bf16x8 afr[4], bfr[4];
#pragma unroll
        for (int i = 0; i < 4; i++)
            afr[i] = *(const bf16x8*)&Al[(wm * 64 + i * 16 + c16) * 40 + kg * 8];
#pragma unroll
        for (int j = 0; j < 4; j++)
            bfr[j] = *(const bf16x8*)&Bl[(wn * 64 + j * 16 + c16) * 40 + kg * 8];
#pragma unroll
        for (int i = 0; i < 4; i++)
#pragma unroll
            for (int j = 0; j < 4; j++)
                acc[i][j] = __builtin_amdgcn_mfma_f32_16x16x32_bf16(afr[i], bfr[j], acc[i][j], 0, 0, 0);
        __syncthreads();
    }

#pragma unroll
    for (int i = 0; i < 4; i++) {
        int row = m0 + wm * 64 + i * 16 + kg * 4;
#pragma unroll
        for (int j = 0; j < 4; j++) {
            int col = n0 + wn * 64 + j * 16 + c16;
            float fb = fcb[col];
#pragma unroll
            for (int r = 0; r < 4; r++)
                out[(size_t)(row + r) * 32000 + col] = acc[i][j][r] + fb;
        }
    }
}

// ---------------- host ----------------
extern "C" void kernel_launch(void* const* d_in, const int* in_sizes, int n_in,
                              void* d_out, int out_size, void* d_ws, size_t ws_size,
                              hipStream_t stream) {
    const int*   seq    = (const int*)d_in[0];
    const float* emb    = (const float*)d_in[2];
    const float* mog1_W = (const float*)d_in[3];
    const float* mog1_b = (const float*)d_in[4];
    const float* W_ih1  = (const float*)d_in[5];
    const float* W_hh1  = (const float*)d_in[6];
    const float* b_ih1  = (const float*)d_in[7];
    const float* b_hh1  = (const float*)d_in[8];
    const float* mog2_W = (const float*)d_in[9];
    const float* mog2_b = (const float*)d_in[10];
    const float* W_ih2  = (const float*)d_in[11];
    const float* W_hh2  = (const float*)d_in[12];
    const float* b_ih2  = (const float*)d_in[13];
    const float* b_hh2  = (const float*)d_in[14];
    const float* fc_b   = (const float*)d_in[15];

    char* ws = (char*)d_ws;
    float* XTF = (float*)ws;                                  // 8 MB
    u16*   XTH = (u16*)(ws + 8388608);                        // 4 MB
    u16*   XTL = (u16*)(ws + 12582912);                       // 4 MB
    float* stF = (float*)(ws + 16777216);                     // 1 MB
    u16*   stH = (u16*)(ws + 17825792);                       // 768 KB
    u32*   bar = (u32*)(ws + 18874368);                       // 16 KB
    unsigned short* hsb = (unsigned short*)(ws + 18890752);   // 4 MB

    float* out0 = (float*)d_out;
    float* hs   = out0 + 65536000LL;

    hipMemsetAsync(stF, 0, 1835008, stream);
    hipMemsetAsync(bar, 0, 16384, stream);

    gather_embed<<<64, 256, 0, stream>>>(seq, emb, XTF, XTH, XTL);

    RArgs a;
    a.m1W = mog1_W; a.m1b = mog1_b;
    a.Wih1 = W_ih1; a.Whh1 = W_hh1; a.bih1 = b_ih1; a.bhh1 = b_hh1;
    a.m2W = mog2_W; a.m2b = mog2_b;
    a.Wih2 = W_ih2; a.Whh2 = W_hh2; a.bih2 = b_ih2; a.bhh2 = b_hh2;
    a.XTF = XTF; a.XTH = XTH; a.XTL = XTL;
    a.stF = stF; a.stH = stH; a.hs = hs; a.bar = bar;

    reck<<<256, 256, 0, stream>>>(a);

    f32_to_bf16<<<1024, 256, 0, stream>>>(hs, hsb, 2097152);
    out_proj<<<dim3(250, 16), 256, 0, stream>>>(hsb, emb, fc_b, out0);
}